// Round 1
// baseline (4510.381 us; speedup 1.0000x reference)
//
#include <hip/hip_runtime.h>
#include <stdint.h>

#define N_NODES 50000
#define N_EDGES 800000
#define IN_CH 64
#define HID 128

#define ENC_NEG_INF 0x007FFFFFu   // enc(-inf)

__device__ __forceinline__ unsigned enc_f32(float f) {
    unsigned u = __float_as_uint(f);
    return (u & 0x80000000u) ? ~u : (u | 0x80000000u);
}
__device__ __forceinline__ float dec_f32(unsigned e) {
    unsigned u = (e & 0x80000000u) ? (e & 0x7FFFFFFFu) : ~e;
    return __uint_as_float(u);
}

// ---------------- utility kernels ----------------

__global__ void fill_u32(unsigned* __restrict__ p, int n, unsigned v) {
    int i = blockIdx.x * blockDim.x + threadIdx.x;
    int stride = gridDim.x * blockDim.x;
    for (; i < n; i += stride) p[i] = v;
}

// Build combined weight WC[K][256]: cols 0..127 = Wtop - Wbot (dst part),
// cols 128..255 = Wbot (src part).  W is [2K][128] row-major.
__global__ void prep_wcat(const float* __restrict__ W, int K, float* __restrict__ WC) {
    int idx = blockIdx.x * 256 + threadIdx.x;
    if (idx >= K * 256) return;
    int k = idx >> 8, c = idx & 255;
    float v;
    if (c < 128) v = W[k * 128 + c] - W[(k + K) * 128 + c];
    else         v = W[(k + K) * 128 + (c - 128)];
    WC[idx] = v;
}

// in-place: encoded u32 -> relu(decoded)  (empty segment: -inf -> 0)
__global__ void relu_decode(unsigned* __restrict__ p, int n) {
    int i = blockIdx.x * blockDim.x + threadIdx.x;
    int stride = gridDim.x * blockDim.x;
    for (; i < n; i += stride) {
        float f = dec_f32(p[i]);
        ((float*)p)[i] = fmaxf(f, 0.0f);
    }
}

// in-place: encoded u32 -> decoded float; empty segment -> 0
__global__ void out_decode(unsigned* __restrict__ p, int n) {
    int i = blockIdx.x * blockDim.x + threadIdx.x;
    int stride = gridDim.x * blockDim.x;
    for (; i < n; i += stride) {
        unsigned e = p[i];
        float f = (e == ENC_NEG_INF) ? 0.0f : dec_f32(e);
        ((float*)p)[i] = f;
    }
}

// ---------------- node-level GEMM: C[M][256] = A[M][K] @ B[K][256] ----------------
// block tile 64x64, thread tile 4x4, K-tile 16
__global__ __launch_bounds__(256) void gemm_uv(const float* __restrict__ A,
                                               const float* __restrict__ B,
                                               float* __restrict__ C,
                                               int M, int K) {
    __shared__ float As[16][64];   // [k][m]
    __shared__ float Bs[16][64];   // [k][n]
    int m0 = blockIdx.x * 64;
    int n0 = blockIdx.y * 64;
    int tid = threadIdx.x;
    int mg = tid & 15, ng = tid >> 4;
    float acc[4][4] = {};

    for (int kt = 0; kt < K; kt += 16) {
        {
            int m = tid >> 2, kq = tid & 3;           // A tile 64 rows x 16 k
            float4 a = make_float4(0.f, 0.f, 0.f, 0.f);
            if (m0 + m < M) a = *(const float4*)&A[(size_t)(m0 + m) * K + kt + 4 * kq];
            As[4 * kq + 0][m] = a.x;
            As[4 * kq + 1][m] = a.y;
            As[4 * kq + 2][m] = a.z;
            As[4 * kq + 3][m] = a.w;
            int k = tid >> 4, nq = tid & 15;          // B tile 16 k x 64 n
            *(float4*)&Bs[k][4 * nq] = *(const float4*)&B[(size_t)(kt + k) * 256 + n0 + 4 * nq];
        }
        __syncthreads();
#pragma unroll
        for (int k = 0; k < 16; ++k) {
            float4 a = *(const float4*)&As[k][4 * mg];
            float4 b = *(const float4*)&Bs[k][4 * ng];
            float av[4] = {a.x, a.y, a.z, a.w};
            float bv[4] = {b.x, b.y, b.z, b.w};
#pragma unroll
            for (int i = 0; i < 4; ++i)
#pragma unroll
                for (int j = 0; j < 4; ++j)
                    acc[i][j] = fmaf(av[i], bv[j], acc[i][j]);
        }
        __syncthreads();
    }
#pragma unroll
    for (int i = 0; i < 4; ++i) {
        int m = m0 + 4 * mg + i;
        if (m < M) {
            float4 o = make_float4(acc[i][0], acc[i][1], acc[i][2], acc[i][3]);
            *(float4*)&C[(size_t)m * 256 + n0 + 4 * ng] = o;
        }
    }
}

// ---------------- edge MLP + max-aggregate ----------------
// Per block: 64 edges. T[e][k] = relu(U[dst[e]][k] + V[src[e]][k] + ba[k]),
// M = T @ Wb + bb, encoded atomicMax into AGG[dst].
__global__ __launch_bounds__(256) void edge_mlp(const float4* __restrict__ UV, // [N][64] f4 (U cols 0..127, V 128..255)
                                                const float* __restrict__ ba,  // [128]
                                                const float* __restrict__ Wb,  // [128][128]
                                                const float* __restrict__ bb,  // [128]
                                                const int* __restrict__ src,
                                                const int* __restrict__ dst,
                                                unsigned* __restrict__ AGG) {  // [N][128] encoded
    __shared__ float Ts[128][64];   // [k][e]
    __shared__ float Ws[16][128];   // streamed Wb k-tile
    int tid = threadIdx.x;
    int e0 = blockIdx.x * 64;
    int lane = tid & 63;
    int w = tid >> 6;
    int s = src[e0 + lane], d = dst[e0 + lane];

    // phase 1: build T (transposed in LDS)
#pragma unroll
    for (int i = 0; i < 8; ++i) {
        int c4 = i * 4 + w;                    // 0..31, each once per block
        float4 u = UV[(size_t)d * 64 + c4];
        float4 v = UV[(size_t)s * 64 + 32 + c4];
        int k0 = c4 * 4;
        Ts[k0 + 0][lane] = fmaxf(u.x + v.x + ba[k0 + 0], 0.f);
        Ts[k0 + 1][lane] = fmaxf(u.y + v.y + ba[k0 + 1], 0.f);
        Ts[k0 + 2][lane] = fmaxf(u.z + v.z + ba[k0 + 2], 0.f);
        Ts[k0 + 3][lane] = fmaxf(u.w + v.w + ba[k0 + 3], 0.f);
    }

    // phase 2: M = T @ Wb   (thread tile: 4 edges x 8 cols)
    int eg = (tid >> 2) & 15;                       // edge group (4 edges)
    int cg = (tid & 3) + ((tid >> 6) << 2);         // col group (8 cols) — bank-friendly
    float acc[4][8] = {};

    for (int kt = 0; kt < 128; kt += 16) {
        __syncthreads();
        {
            int k = tid >> 4, nq = tid & 15;
            *(float4*)&Ws[k][4 * nq]      = *(const float4*)&Wb[(size_t)(kt + k) * 128 + 4 * nq];
            *(float4*)&Ws[k][64 + 4 * nq] = *(const float4*)&Wb[(size_t)(kt + k) * 128 + 64 + 4 * nq];
        }
        __syncthreads();
#pragma unroll
        for (int kk = 0; kk < 16; ++kk) {
            float4 t  = *(const float4*)&Ts[kt + kk][4 * eg];
            float4 w0 = *(const float4*)&Ws[kk][8 * cg];
            float4 w1 = *(const float4*)&Ws[kk][8 * cg + 4];
            float tv[4] = {t.x, t.y, t.z, t.w};
            float wv[8] = {w0.x, w0.y, w0.z, w0.w, w1.x, w1.y, w1.z, w1.w};
#pragma unroll
            for (int i = 0; i < 4; ++i)
#pragma unroll
                for (int j = 0; j < 8; ++j)
                    acc[i][j] = fmaf(tv[i], wv[j], acc[i][j]);
        }
    }

    // epilogue: add bb, encoded atomic max at dst
    float4 bbl = *(const float4*)&bb[8 * cg];
    float4 bbh = *(const float4*)&bb[8 * cg + 4];
    float bv[8] = {bbl.x, bbl.y, bbl.z, bbl.w, bbh.x, bbh.y, bbh.z, bbh.w};
#pragma unroll
    for (int i = 0; i < 4; ++i) {
        int de = dst[e0 + 4 * eg + i];
        unsigned* row = &AGG[(size_t)de * 128 + 8 * cg];
#pragma unroll
        for (int j = 0; j < 8; ++j) {
            float m = acc[i][j] + bv[j];
            atomicMax(&row[j], enc_f32(m));
        }
    }
}

// ---------------- launch ----------------

extern "C" void kernel_launch(void* const* d_in, const int* in_sizes, int n_in,
                              void* d_out, int out_size, void* d_ws, size_t ws_size,
                              hipStream_t stream) {
    const float* x   = (const float*)d_in[0];
    const int*   ei  = (const int*)d_in[1];
    const float* W1a = (const float*)d_in[2];
    const float* b1a = (const float*)d_in[3];
    const float* W1b = (const float*)d_in[4];
    const float* b1b = (const float*)d_in[5];
    const float* W2a = (const float*)d_in[6];
    const float* b2a = (const float*)d_in[7];
    const float* W2b = (const float*)d_in[8];
    const float* b2b = (const float*)d_in[9];
    const int* src = ei;
    const int* dst = ei + N_EDGES;

    char* ws = (char*)d_ws;
    float*    UV   = (float*)ws;                               // 50000*256*4 = 51.2 MB
    unsigned* AGG1 = (unsigned*)(ws + 51200000);               // 50000*128*4 = 25.6 MB
    float*    WC1  = (float*)(ws + 76800000);                  // 64 KB
    float*    WC2  = (float*)(ws + 76800000 + 65536);          // 128 KB

    const int NH = N_NODES * HID;   // 6.4M

    prep_wcat<<<64, 256, 0, stream>>>(W1a, 64, WC1);
    prep_wcat<<<128, 256, 0, stream>>>(W2a, 128, WC2);
    fill_u32<<<2048, 256, 0, stream>>>(AGG1, NH, ENC_NEG_INF);
    fill_u32<<<2048, 256, 0, stream>>>((unsigned*)d_out, NH, ENC_NEG_INF);

    // Layer 1
    gemm_uv<<<dim3(782, 4), 256, 0, stream>>>(x, WC1, UV, N_NODES, 64);
    edge_mlp<<<N_EDGES / 64, 256, 0, stream>>>((const float4*)UV, b1a, W1b, b1b, src, dst, AGG1);
    relu_decode<<<2048, 256, 0, stream>>>(AGG1, NH);   // AGG1 buffer becomes H (f32)

    // Layer 2
    gemm_uv<<<dim3(782, 4), 256, 0, stream>>>((const float*)AGG1, WC2, UV, N_NODES, 128);
    edge_mlp<<<N_EDGES / 64, 256, 0, stream>>>((const float4*)UV, b2a, W2b, b2b, src, dst, (unsigned*)d_out);
    out_decode<<<2048, 256, 0, stream>>>((unsigned*)d_out, NH);
}

// Round 2
// 1179.542 us; speedup vs baseline: 3.8238x; 3.8238x over previous
//
#include <hip/hip_runtime.h>
#include <stdint.h>

#define N_NODES 50000
#define N_EDGES 800000
#define IN_CH 64
#define HID 128

#define ENC_NEG_INF 0x007FFFFFu   // enc(-inf)

__device__ __forceinline__ unsigned enc_f32(float f) {
    unsigned u = __float_as_uint(f);
    return (u & 0x80000000u) ? ~u : (u | 0x80000000u);
}
__device__ __forceinline__ float dec_f32(unsigned e) {
    unsigned u = (e & 0x80000000u) ? (e & 0x7FFFFFFFu) : ~e;
    return __uint_as_float(u);
}

// ---------------- utility kernels ----------------

__global__ void fill_u32(unsigned* __restrict__ p, int n, unsigned v) {
    int i = blockIdx.x * blockDim.x + threadIdx.x;
    int stride = gridDim.x * blockDim.x;
    for (; i < n; i += stride) p[i] = v;
}

// Build combined weight WC[K][256]: cols 0..127 = Wtop - Wbot (dst part),
// cols 128..255 = Wbot (src part).  W is [2K][128] row-major.
__global__ void prep_wcat(const float* __restrict__ W, int K, float* __restrict__ WC) {
    int idx = blockIdx.x * 256 + threadIdx.x;
    if (idx >= K * 256) return;
    int k = idx >> 8, c = idx & 255;
    float v;
    if (c < 128) v = W[k * 128 + c] - W[(k + K) * 128 + c];
    else         v = W[(k + K) * 128 + (c - 128)];
    WC[idx] = v;
}

// in-place: encoded u32 -> relu(decoded)  (empty segment: -inf -> 0)
__global__ void relu_decode(unsigned* __restrict__ p, int n) {
    int i = blockIdx.x * blockDim.x + threadIdx.x;
    int stride = gridDim.x * blockDim.x;
    for (; i < n; i += stride) {
        float f = dec_f32(p[i]);
        ((float*)p)[i] = fmaxf(f, 0.0f);
    }
}

// in-place: encoded u32 -> decoded float; empty segment -> 0
__global__ void out_decode(unsigned* __restrict__ p, int n) {
    int i = blockIdx.x * blockDim.x + threadIdx.x;
    int stride = gridDim.x * blockDim.x;
    for (; i < n; i += stride) {
        unsigned e = p[i];
        float f = (e == ENC_NEG_INF) ? 0.0f : dec_f32(e);
        ((float*)p)[i] = f;
    }
}

// ---------------- sort-by-dst (counting sort) ----------------

__global__ void hist_dst(const int* __restrict__ dst, unsigned* __restrict__ count) {
    int i = blockIdx.x * blockDim.x + threadIdx.x;
    if (i < N_EDGES) atomicAdd(&count[dst[i]], 1u);
}

// single block, 1024 threads: exclusive prefix sum of count[50000] -> cursor
__global__ __launch_bounds__(1024) void scan_offsets(const unsigned* __restrict__ count,
                                                     unsigned* __restrict__ cursor) {
    __shared__ unsigned sums[1024];
    const int PER = 49;                   // 1024*49 = 50176 >= 50000
    int t = threadIdx.x;
    int base = t * PER;
    unsigned s = 0;
    for (int i = 0; i < PER; ++i) {
        int idx = base + i;
        if (idx < N_NODES) s += count[idx];
    }
    sums[t] = s;
    __syncthreads();
    for (int off = 1; off < 1024; off <<= 1) {
        unsigned v = (t >= off) ? sums[t - off] : 0u;
        __syncthreads();
        sums[t] += v;
        __syncthreads();
    }
    unsigned ex = sums[t] - s;            // exclusive prefix for this chunk
    for (int i = 0; i < PER; ++i) {
        int idx = base + i;
        if (idx < N_NODES) { cursor[idx] = ex; ex += count[idx]; }
    }
}

__global__ void scatter_edges(const int* __restrict__ src, const int* __restrict__ dst,
                              unsigned* __restrict__ cursor,
                              int* __restrict__ ssrc, int* __restrict__ sdst) {
    int i = blockIdx.x * blockDim.x + threadIdx.x;
    if (i < N_EDGES) {
        int d = dst[i];
        unsigned p = atomicAdd(&cursor[d], 1u);
        ssrc[p] = src[i];
        sdst[p] = d;
    }
}

// ---------------- node-level GEMM: C[M][256] = A[M][K] @ B[K][256] ----------------
__global__ __launch_bounds__(256) void gemm_uv(const float* __restrict__ A,
                                               const float* __restrict__ B,
                                               float* __restrict__ C,
                                               int M, int K) {
    __shared__ float As[16][64];   // [k][m]
    __shared__ float Bs[16][64];   // [k][n]
    int m0 = blockIdx.x * 64;
    int n0 = blockIdx.y * 64;
    int tid = threadIdx.x;
    int mg = tid & 15, ng = tid >> 4;
    float acc[4][4] = {};

    for (int kt = 0; kt < K; kt += 16) {
        {
            int m = tid >> 2, kq = tid & 3;
            float4 a = make_float4(0.f, 0.f, 0.f, 0.f);
            if (m0 + m < M) a = *(const float4*)&A[(size_t)(m0 + m) * K + kt + 4 * kq];
            As[4 * kq + 0][m] = a.x;
            As[4 * kq + 1][m] = a.y;
            As[4 * kq + 2][m] = a.z;
            As[4 * kq + 3][m] = a.w;
            int k = tid >> 4, nq = tid & 15;
            *(float4*)&Bs[k][4 * nq] = *(const float4*)&B[(size_t)(kt + k) * 256 + n0 + 4 * nq];
        }
        __syncthreads();
#pragma unroll
        for (int k = 0; k < 16; ++k) {
            float4 a = *(const float4*)&As[k][4 * mg];
            float4 b = *(const float4*)&Bs[k][4 * ng];
            float av[4] = {a.x, a.y, a.z, a.w};
            float bv[4] = {b.x, b.y, b.z, b.w};
#pragma unroll
            for (int i = 0; i < 4; ++i)
#pragma unroll
                for (int j = 0; j < 4; ++j)
                    acc[i][j] = fmaf(av[i], bv[j], acc[i][j]);
        }
        __syncthreads();
    }
#pragma unroll
    for (int i = 0; i < 4; ++i) {
        int m = m0 + 4 * mg + i;
        if (m < M) {
            float4 o = make_float4(acc[i][0], acc[i][1], acc[i][2], acc[i][3]);
            *(float4*)&C[(size_t)m * 256 + n0 + 4 * ng] = o;
        }
    }
}

// ---------------- edge MLP + segmented max-aggregate (edges sorted by dst) ----------------
// Per block: 64 sorted edges. T[e][k] = relu(U[dst]+V[src]+ba), M = T@Wb + bb,
// then block-level segmented max over sorted dst runs, one atomicMax per run.
__global__ __launch_bounds__(256) void edge_mlp(const float4* __restrict__ UV, // [N][64] f4
                                                const float* __restrict__ ba,  // [128]
                                                const float* __restrict__ Wb,  // [128][128]
                                                const float* __restrict__ bb,  // [128]
                                                const int* __restrict__ ssrc,
                                                const int* __restrict__ sdst,
                                                unsigned* __restrict__ AGG) {  // [N][128] encoded
    __shared__ float buf[128 * 65];      // phase A: Ts[k][e] (stride 64); phase B: M2[c][e] (stride 65)
    __shared__ float Ws[16][128];
    __shared__ int sdst_s[64];
    int tid = threadIdx.x;
    int e0 = blockIdx.x * 64;
    int lane = tid & 63;
    int w = tid >> 6;
    int s = ssrc[e0 + lane], d = sdst[e0 + lane];
    if (w == 0) sdst_s[lane] = d;

    // phase 1: build T (transposed in LDS, stride 64)
#pragma unroll
    for (int i = 0; i < 8; ++i) {
        int c4 = i * 4 + w;
        float4 u = UV[(size_t)d * 64 + c4];
        float4 v = UV[(size_t)s * 64 + 32 + c4];
        int k0 = c4 * 4;
        buf[(k0 + 0) * 64 + lane] = fmaxf(u.x + v.x + ba[k0 + 0], 0.f);
        buf[(k0 + 1) * 64 + lane] = fmaxf(u.y + v.y + ba[k0 + 1], 0.f);
        buf[(k0 + 2) * 64 + lane] = fmaxf(u.z + v.z + ba[k0 + 2], 0.f);
        buf[(k0 + 3) * 64 + lane] = fmaxf(u.w + v.w + ba[k0 + 3], 0.f);
    }

    // phase 2: M = T @ Wb   (thread tile: 4 edges x 8 cols)
    int eg = (tid >> 2) & 15;
    int cg = (tid & 3) + ((tid >> 6) << 2);
    float acc[4][8] = {};

    for (int kt = 0; kt < 128; kt += 16) {
        __syncthreads();
        {
            int k = tid >> 4, nq = tid & 15;
            *(float4*)&Ws[k][4 * nq]      = *(const float4*)&Wb[(size_t)(kt + k) * 128 + 4 * nq];
            *(float4*)&Ws[k][64 + 4 * nq] = *(const float4*)&Wb[(size_t)(kt + k) * 128 + 64 + 4 * nq];
        }
        __syncthreads();
#pragma unroll
        for (int kk = 0; kk < 16; ++kk) {
            float4 t  = *(const float4*)&buf[(kt + kk) * 64 + 4 * eg];
            float4 w0 = *(const float4*)&Ws[kk][8 * cg];
            float4 w1 = *(const float4*)&Ws[kk][8 * cg + 4];
            float tv[4] = {t.x, t.y, t.z, t.w};
            float wv[8] = {w0.x, w0.y, w0.z, w0.w, w1.x, w1.y, w1.z, w1.w};
#pragma unroll
            for (int i = 0; i < 4; ++i)
#pragma unroll
                for (int j = 0; j < 8; ++j)
                    acc[i][j] = fmaf(tv[i], wv[j], acc[i][j]);
        }
    }

    // phase 3: deposit M (+bb) into LDS as M2[c][e], stride 65 (conflict-free reduce reads)
    float4 bbl = *(const float4*)&bb[8 * cg];
    float4 bbh = *(const float4*)&bb[8 * cg + 4];
    float bv[8] = {bbl.x, bbl.y, bbl.z, bbl.w, bbh.x, bbh.y, bbh.z, bbh.w};
    __syncthreads();   // done reading Ts
#pragma unroll
    for (int i = 0; i < 4; ++i)
#pragma unroll
        for (int j = 0; j < 8; ++j)
            buf[(8 * cg + j) * 65 + 4 * eg + i] = acc[i][j] + bv[j];
    __syncthreads();

    // phase 4: segmented max over sorted dst runs; one atomicMax per (run, col)
    {
        int c = tid & 127;
        int h = tid >> 7;
        int eb = h * 32;
        int cur = sdst_s[eb];
        float m = -3.402823466e38f;
        for (int e = eb; e < eb + 32; ++e) {
            int de = sdst_s[e];
            if (de != cur) {
                atomicMax(&AGG[(size_t)cur * 128 + c], enc_f32(m));
                cur = de;
                m = -3.402823466e38f;
            }
            m = fmaxf(m, buf[c * 65 + e]);
        }
        atomicMax(&AGG[(size_t)cur * 128 + c], enc_f32(m));
    }
}

// ---------------- launch ----------------

extern "C" void kernel_launch(void* const* d_in, const int* in_sizes, int n_in,
                              void* d_out, int out_size, void* d_ws, size_t ws_size,
                              hipStream_t stream) {
    const float* x   = (const float*)d_in[0];
    const int*   ei  = (const int*)d_in[1];
    const float* W1a = (const float*)d_in[2];
    const float* b1a = (const float*)d_in[3];
    const float* W1b = (const float*)d_in[4];
    const float* b1b = (const float*)d_in[5];
    const float* W2a = (const float*)d_in[6];
    const float* b2a = (const float*)d_in[7];
    const float* W2b = (const float*)d_in[8];
    const float* b2b = (const float*)d_in[9];
    const int* src = ei;
    const int* dst = ei + N_EDGES;

    char* ws = (char*)d_ws;
    float*    UV    = (float*)ws;                                // 51.2 MB
    unsigned* AGG1  = (unsigned*)(ws + 51200000);                // 25.6 MB
    float*    WC1   = (float*)(ws + 76800000);                   // 64 KB
    float*    WC2   = (float*)(ws + 76865536);                   // 128 KB
    int*      ssrc  = (int*)(ws + 76996608);                     // 3.2 MB
    int*      sdst  = (int*)(ws + 80196608);                     // 3.2 MB
    unsigned* count = (unsigned*)(ws + 83396608);                // 200 KB
    unsigned* cursor= (unsigned*)(ws + 83596608);                // 200 KB

    const int NH = N_NODES * HID;   // 6.4M

    prep_wcat<<<64, 256, 0, stream>>>(W1a, 64, WC1);
    prep_wcat<<<128, 256, 0, stream>>>(W2a, 128, WC2);
    fill_u32<<<2048, 256, 0, stream>>>(AGG1, NH, ENC_NEG_INF);
    fill_u32<<<2048, 256, 0, stream>>>((unsigned*)d_out, NH, ENC_NEG_INF);
    fill_u32<<<196, 256, 0, stream>>>(count, N_NODES, 0u);

    // counting sort of edges by dst (max is order-independent -> output deterministic)
    hist_dst<<<3125, 256, 0, stream>>>(dst, count);
    scan_offsets<<<1, 1024, 0, stream>>>(count, cursor);
    scatter_edges<<<3125, 256, 0, stream>>>(src, dst, cursor, ssrc, sdst);

    // Layer 1
    gemm_uv<<<dim3(782, 4), 256, 0, stream>>>(x, WC1, UV, N_NODES, 64);
    edge_mlp<<<N_EDGES / 64, 256, 0, stream>>>((const float4*)UV, b1a, W1b, b1b, ssrc, sdst, AGG1);
    relu_decode<<<2048, 256, 0, stream>>>(AGG1, NH);

    // Layer 2
    gemm_uv<<<dim3(782, 4), 256, 0, stream>>>((const float*)AGG1, WC2, UV, N_NODES, 128);
    edge_mlp<<<N_EDGES / 64, 256, 0, stream>>>((const float4*)UV, b2a, W2b, b2b, ssrc, sdst, (unsigned*)d_out);
    out_decode<<<2048, 256, 0, stream>>>((unsigned*)d_out, NH);
}

// Round 3
// 814.272 us; speedup vs baseline: 5.5392x; 1.4486x over previous
//
#include <hip/hip_runtime.h>
#include <stdint.h>

#define N_NODES 50000
#define N_EDGES 800000
#define HID 128

#define ENC_NEG_INF 0x007FFFFFu   // enc(-inf)

typedef short short8 __attribute__((ext_vector_type(8)));
typedef float f32x4 __attribute__((ext_vector_type(4)));

__device__ __forceinline__ unsigned enc_f32(float f) {
    unsigned u = __float_as_uint(f);
    return (u & 0x80000000u) ? ~u : (u | 0x80000000u);
}
__device__ __forceinline__ float dec_f32(unsigned e) {
    unsigned u = (e & 0x80000000u) ? (e & 0x7FFFFFFFu) : ~e;
    return __uint_as_float(u);
}
__device__ __forceinline__ unsigned short f2bf(float f) {
    unsigned u = __float_as_uint(f);
    unsigned r = (u + 0x7fffu + ((u >> 16) & 1u)) >> 16;
    return (unsigned short)r;
}
__device__ __forceinline__ float bf2f(unsigned short h) {
    return __uint_as_float(((unsigned)h) << 16);
}

// ---------------- utility kernels ----------------

__global__ void fill_u32(unsigned* __restrict__ p, int n, unsigned v) {
    int i = blockIdx.x * blockDim.x + threadIdx.x;
    int stride = gridDim.x * blockDim.x;
    for (; i < n; i += stride) p[i] = v;
}

// Build combined weight WC[K][256]: cols 0..127 = Wtop - Wbot, 128..255 = Wbot
__global__ void prep_wcat(const float* __restrict__ W, int K, float* __restrict__ WC) {
    int idx = blockIdx.x * 256 + threadIdx.x;
    if (idx >= K * 256) return;
    int k = idx >> 8, c = idx & 255;
    float v;
    if (c < 128) v = W[k * 128 + c] - W[(k + K) * 128 + c];
    else         v = W[(k + K) * 128 + (c - 128)];
    WC[idx] = v;
}

// Wb[128][128] -> MFMA B-fragment layout, hi plane then lo plane (16384 shorts each)
// Wg[(kt*8+nt)*64 + lane][j] = bf16 of Wb[32kt + 8*(lane>>4) + j][16nt + (lane&15)]
__global__ void prep_wfrag(const float* __restrict__ Wb, unsigned short* __restrict__ Wg) {
    int idx = blockIdx.x * 256 + threadIdx.x;   // 0..16383
    int j = idx & 7, lane = (idx >> 3) & 63, nt = (idx >> 9) & 7, kt = idx >> 12;
    int k = 32 * kt + 8 * (lane >> 4) + j;
    int n = 16 * nt + (lane & 15);
    float w = Wb[k * 128 + n];
    unsigned short hi = f2bf(w);
    float lo = w - bf2f(hi);
    Wg[idx] = hi;
    Wg[16384 + idx] = f2bf(lo);
}

__global__ void relu_decode(unsigned* __restrict__ p, int n) {
    int i = blockIdx.x * blockDim.x + threadIdx.x;
    int stride = gridDim.x * blockDim.x;
    for (; i < n; i += stride) {
        float f = dec_f32(p[i]);
        ((float*)p)[i] = fmaxf(f, 0.0f);
    }
}

__global__ void out_decode(unsigned* __restrict__ p, int n) {
    int i = blockIdx.x * blockDim.x + threadIdx.x;
    int stride = gridDim.x * blockDim.x;
    for (; i < n; i += stride) {
        unsigned e = p[i];
        float f = (e == ENC_NEG_INF) ? 0.0f : dec_f32(e);
        ((float*)p)[i] = f;
    }
}

// ---------------- sort-by-dst (counting sort) ----------------

__global__ void hist_dst(const int* __restrict__ dst, unsigned* __restrict__ count) {
    int i = blockIdx.x * blockDim.x + threadIdx.x;
    if (i < N_EDGES) atomicAdd(&count[dst[i]], 1u);
}

__global__ __launch_bounds__(1024) void scan_offsets(const unsigned* __restrict__ count,
                                                     unsigned* __restrict__ cursor) {
    __shared__ unsigned sums[1024];
    const int PER = 49;
    int t = threadIdx.x;
    int base = t * PER;
    unsigned s = 0;
    for (int i = 0; i < PER; ++i) {
        int idx = base + i;
        if (idx < N_NODES) s += count[idx];
    }
    sums[t] = s;
    __syncthreads();
    for (int off = 1; off < 1024; off <<= 1) {
        unsigned v = (t >= off) ? sums[t - off] : 0u;
        __syncthreads();
        sums[t] += v;
        __syncthreads();
    }
    unsigned ex = sums[t] - s;
    for (int i = 0; i < PER; ++i) {
        int idx = base + i;
        if (idx < N_NODES) { cursor[idx] = ex; ex += count[idx]; }
    }
}

__global__ void scatter_edges(const int* __restrict__ src, const int* __restrict__ dst,
                              unsigned* __restrict__ cursor,
                              int* __restrict__ ssrc, int* __restrict__ sdst) {
    int i = blockIdx.x * blockDim.x + threadIdx.x;
    if (i < N_EDGES) {
        int d = dst[i];
        unsigned p = atomicAdd(&cursor[d], 1u);
        ssrc[p] = src[i];
        sdst[p] = d;
    }
}

// ---------------- node-level GEMM: C[M][256] = A[M][K] @ B[K][256] ----------------
__global__ __launch_bounds__(256) void gemm_uv(const float* __restrict__ A,
                                               const float* __restrict__ B,
                                               float* __restrict__ C,
                                               int M, int K) {
    __shared__ float As[16][64];
    __shared__ float Bs[16][64];
    int m0 = blockIdx.x * 64;
    int n0 = blockIdx.y * 64;
    int tid = threadIdx.x;
    int mg = tid & 15, ng = tid >> 4;
    float acc[4][4] = {};

    for (int kt = 0; kt < K; kt += 16) {
        {
            int m = tid >> 2, kq = tid & 3;
            float4 a = make_float4(0.f, 0.f, 0.f, 0.f);
            if (m0 + m < M) a = *(const float4*)&A[(size_t)(m0 + m) * K + kt + 4 * kq];
            As[4 * kq + 0][m] = a.x;
            As[4 * kq + 1][m] = a.y;
            As[4 * kq + 2][m] = a.z;
            As[4 * kq + 3][m] = a.w;
            int k = tid >> 4, nq = tid & 15;
            *(float4*)&Bs[k][4 * nq] = *(const float4*)&B[(size_t)(kt + k) * 256 + n0 + 4 * nq];
        }
        __syncthreads();
#pragma unroll
        for (int k = 0; k < 16; ++k) {
            float4 a = *(const float4*)&As[k][4 * mg];
            float4 b = *(const float4*)&Bs[k][4 * ng];
            float av[4] = {a.x, a.y, a.z, a.w};
            float bv[4] = {b.x, b.y, b.z, b.w};
#pragma unroll
            for (int i = 0; i < 4; ++i)
#pragma unroll
                for (int j = 0; j < 4; ++j)
                    acc[i][j] = fmaf(av[i], bv[j], acc[i][j]);
        }
        __syncthreads();
    }
#pragma unroll
    for (int i = 0; i < 4; ++i) {
        int m = m0 + 4 * mg + i;
        if (m < M) {
            float4 o = make_float4(acc[i][0], acc[i][1], acc[i][2], acc[i][3]);
            *(float4*)&C[(size_t)m * 256 + n0 + 4 * ng] = o;
        }
    }
}

// ---------------- MFMA edge MLP + segmented max-aggregate ----------------
// 128 sorted edges / block, 4 waves, wave = 32 edges (2 row-tiles).
// A = T (built in regs from U/V gather, bf16 hi/lo), B = W frags from LDS.
__global__ __launch_bounds__(256, 2) void edge_mlp_mfma(
        const float* __restrict__ UV,          // [N][256]: U cols 0..127, V 128..255
        const float* __restrict__ ba,          // [128]
        const unsigned short* __restrict__ Wg, // frag layout, hi|lo, 32768 shorts
        const float* __restrict__ bb,          // [128]
        const int* __restrict__ ssrc,
        const int* __restrict__ sdst,
        unsigned* __restrict__ AGG) {          // [N][128] encoded
    __shared__ char lds[65536];                // phase A: W frags; phase B: M2[128e][128c] f32
    int tid = threadIdx.x;
    int e0 = blockIdx.x * 128;
    int w = tid >> 6, l = tid & 63;
    int q = l >> 4, m = l & 15;

    // stage W fragments (64KB) into LDS
    {
        const float4* s4 = (const float4*)Wg;
        float4* d4 = (float4*)lds;
#pragma unroll
        for (int i = 0; i < 16; ++i) d4[tid + 256 * i] = s4[tid + 256 * i];
    }

    // phase 1: build A fragments in registers (bf16 hi/lo split)
    short8 ahi[2][4], alo[2][4];
#pragma unroll
    for (int mt = 0; mt < 2; ++mt) {
        int e = e0 + 32 * w + 16 * mt + m;
        int d = sdst[e], s = ssrc[e];
        const float4* Ud = (const float4*)&UV[(size_t)d * 256];
        const float4* Vs = (const float4*)&UV[(size_t)s * 256 + 128];
#pragma unroll
        for (int kt = 0; kt < 4; ++kt) {
            float4 u0 = Ud[8 * kt + 2 * q], u1 = Ud[8 * kt + 2 * q + 1];
            float4 v0 = Vs[8 * kt + 2 * q], v1 = Vs[8 * kt + 2 * q + 1];
            float4 a0 = *(const float4*)&ba[32 * kt + 8 * q];
            float4 a1 = *(const float4*)&ba[32 * kt + 8 * q + 4];
            float t[8];
            t[0] = fmaxf(u0.x + v0.x + a0.x, 0.f);
            t[1] = fmaxf(u0.y + v0.y + a0.y, 0.f);
            t[2] = fmaxf(u0.z + v0.z + a0.z, 0.f);
            t[3] = fmaxf(u0.w + v0.w + a0.w, 0.f);
            t[4] = fmaxf(u1.x + v1.x + a1.x, 0.f);
            t[5] = fmaxf(u1.y + v1.y + a1.y, 0.f);
            t[6] = fmaxf(u1.z + v1.z + a1.z, 0.f);
            t[7] = fmaxf(u1.w + v1.w + a1.w, 0.f);
            short8 hi, lo;
#pragma unroll
            for (int j = 0; j < 8; ++j) {
                unsigned short h = f2bf(t[j]);
                hi[j] = (short)h;
                lo[j] = (short)f2bf(t[j] - bf2f(h));
            }
            ahi[mt][kt] = hi;
            alo[mt][kt] = lo;
        }
    }
    __syncthreads();   // W frags visible

    // phase 2: MFMA  (D = T @ W), 3-product hi/lo split
    f32x4 acc[2][8];
#pragma unroll
    for (int mt = 0; mt < 2; ++mt)
#pragma unroll
        for (int nt = 0; nt < 8; ++nt)
            acc[mt][nt] = (f32x4){0.f, 0.f, 0.f, 0.f};

    const short8* bfr = (const short8*)lds;    // [(kt*8+nt)*64 + lane]
#pragma unroll
    for (int nt = 0; nt < 8; ++nt) {
#pragma unroll
        for (int kt = 0; kt < 4; ++kt) {
            short8 bhi = bfr[(kt * 8 + nt) * 64 + l];
            short8 blo = bfr[2048 + (kt * 8 + nt) * 64 + l];
#pragma unroll
            for (int mt = 0; mt < 2; ++mt) {
                acc[mt][nt] = __builtin_amdgcn_mfma_f32_16x16x32_bf16(ahi[mt][kt], bhi, acc[mt][nt], 0, 0, 0);
                acc[mt][nt] = __builtin_amdgcn_mfma_f32_16x16x32_bf16(alo[mt][kt], bhi, acc[mt][nt], 0, 0, 0);
                acc[mt][nt] = __builtin_amdgcn_mfma_f32_16x16x32_bf16(ahi[mt][kt], blo, acc[mt][nt], 0, 0, 0);
            }
        }
    }
    __syncthreads();   // everyone done reading W frags

    // phase 3: M2[e][c] = acc + bb   (D layout: col=16nt+m, row=32w+16mt+4q+r)
    float* M2 = (float*)lds;
#pragma unroll
    for (int nt = 0; nt < 8; ++nt) {
        float bbv = bb[16 * nt + m];
#pragma unroll
        for (int mt = 0; mt < 2; ++mt)
#pragma unroll
            for (int r = 0; r < 4; ++r)
                M2[(32 * w + 16 * mt + 4 * q + r) * 128 + 16 * nt + m] = acc[mt][nt][r] + bbv;
    }
    __syncthreads();

    // phase 4: segmented max over sorted dst runs; one atomicMax per run
    {
        int c = tid & 127, h = tid >> 7;
        int eb = 64 * h;
        int cur = sdst[e0 + eb];
        float mx = -3.402823466e38f;
        for (int e = eb; e < eb + 64; ++e) {
            int de = sdst[e0 + e];
            if (de != cur) {
                atomicMax(&AGG[(size_t)cur * 128 + c], enc_f32(mx));
                cur = de;
                mx = -3.402823466e38f;
            }
            mx = fmaxf(mx, M2[e * 128 + c]);
        }
        atomicMax(&AGG[(size_t)cur * 128 + c], enc_f32(mx));
    }
}

// ---------------- launch ----------------

extern "C" void kernel_launch(void* const* d_in, const int* in_sizes, int n_in,
                              void* d_out, int out_size, void* d_ws, size_t ws_size,
                              hipStream_t stream) {
    const float* x   = (const float*)d_in[0];
    const int*   ei  = (const int*)d_in[1];
    const float* W1a = (const float*)d_in[2];
    const float* b1a = (const float*)d_in[3];
    const float* W1b = (const float*)d_in[4];
    const float* b1b = (const float*)d_in[5];
    const float* W2a = (const float*)d_in[6];
    const float* b2a = (const float*)d_in[7];
    const float* W2b = (const float*)d_in[8];
    const float* b2b = (const float*)d_in[9];
    const int* src = ei;
    const int* dst = ei + N_EDGES;

    char* ws = (char*)d_ws;
    float*          UV    = (float*)ws;                          // 51.2 MB
    unsigned*       AGG1  = (unsigned*)(ws + 51200000);          // 25.6 MB
    float*          WC1   = (float*)(ws + 76800000);             // 64 KB
    float*          WC2   = (float*)(ws + 76865536);             // 128 KB
    int*            ssrc  = (int*)(ws + 76996608);               // 3.2 MB
    int*            sdst  = (int*)(ws + 80196608);               // 3.2 MB
    unsigned*       count = (unsigned*)(ws + 83396608);          // 200 KB
    unsigned*       cursor= (unsigned*)(ws + 83596608);          // 200 KB
    unsigned short* Wg1   = (unsigned short*)(ws + 83796608);    // 64 KB
    unsigned short* Wg2   = (unsigned short*)(ws + 83862144);    // 64 KB

    const int NH = N_NODES * HID;   // 6.4M

    prep_wcat<<<64, 256, 0, stream>>>(W1a, 64, WC1);
    prep_wcat<<<128, 256, 0, stream>>>(W2a, 128, WC2);
    prep_wfrag<<<64, 256, 0, stream>>>(W1b, Wg1);
    prep_wfrag<<<64, 256, 0, stream>>>(W2b, Wg2);
    fill_u32<<<2048, 256, 0, stream>>>(AGG1, NH, ENC_NEG_INF);
    fill_u32<<<2048, 256, 0, stream>>>((unsigned*)d_out, NH, ENC_NEG_INF);
    fill_u32<<<196, 256, 0, stream>>>(count, N_NODES, 0u);

    // counting sort of edges by dst (max is order-independent -> deterministic)
    hist_dst<<<3125, 256, 0, stream>>>(dst, count);
    scan_offsets<<<1, 1024, 0, stream>>>(count, cursor);
    scatter_edges<<<3125, 256, 0, stream>>>(src, dst, cursor, ssrc, sdst);

    // Layer 1
    gemm_uv<<<dim3(782, 4), 256, 0, stream>>>(x, WC1, UV, N_NODES, 64);
    edge_mlp_mfma<<<N_EDGES / 128, 256, 0, stream>>>(UV, b1a, Wg1, b1b, ssrc, sdst, AGG1);
    relu_decode<<<2048, 256, 0, stream>>>(AGG1, NH);

    // Layer 2
    gemm_uv<<<dim3(782, 4), 256, 0, stream>>>((const float*)AGG1, WC2, UV, N_NODES, 128);
    edge_mlp_mfma<<<N_EDGES / 128, 256, 0, stream>>>(UV, b2a, Wg2, b2b, ssrc, sdst, (unsigned*)d_out);
    out_decode<<<2048, 256, 0, stream>>>((unsigned*)d_out, NH);
}

// Round 4
// 487.492 us; speedup vs baseline: 9.2522x; 1.6703x over previous
//
#include <hip/hip_runtime.h>
#include <stdint.h>

#define N_NODES 50000
#define N_EDGES 800000
#define HID 128

#define ENC_NEG_INF 0x007FFFFFu   // enc(-inf)

typedef short short8 __attribute__((ext_vector_type(8)));
typedef float f32x4 __attribute__((ext_vector_type(4)));

__device__ __forceinline__ unsigned enc_f32(float f) {
    unsigned u = __float_as_uint(f);
    return (u & 0x80000000u) ? ~u : (u | 0x80000000u);
}
__device__ __forceinline__ float dec_f32(unsigned e) {
    unsigned u = (e & 0x80000000u) ? (e & 0x7FFFFFFFu) : ~e;
    return __uint_as_float(u);
}
__device__ __forceinline__ unsigned short f2bf(float f) {
    unsigned u = __float_as_uint(f);
    unsigned r = (u + 0x7fffu + ((u >> 16) & 1u)) >> 16;
    return (unsigned short)r;
}
__device__ __forceinline__ float bf2f(unsigned short h) {
    return __uint_as_float(((unsigned)h) << 16);
}

// ---------------- utility kernels ----------------

__global__ void fill_u32(unsigned* __restrict__ p, int n, unsigned v) {
    int i = blockIdx.x * blockDim.x + threadIdx.x;
    int stride = gridDim.x * blockDim.x;
    for (; i < n; i += stride) p[i] = v;
}

// Build combined weight WC[K][256]: cols 0..127 = Wtop - Wbot, 128..255 = Wbot
__global__ void prep_wcat(const float* __restrict__ W, int K, float* __restrict__ WC) {
    int idx = blockIdx.x * 256 + threadIdx.x;
    if (idx >= K * 256) return;
    int k = idx >> 8, c = idx & 255;
    float v;
    if (c < 128) v = W[k * 128 + c] - W[(k + K) * 128 + c];
    else         v = W[(k + K) * 128 + (c - 128)];
    WC[idx] = v;
}

// Wb[128][128] -> MFMA B-fragment layout, hi plane then lo plane (16384 shorts each)
__global__ void prep_wfrag(const float* __restrict__ Wb, unsigned short* __restrict__ Wg) {
    int idx = blockIdx.x * 256 + threadIdx.x;   // 0..16383
    int j = idx & 7, lane = (idx >> 3) & 63, nt = (idx >> 9) & 7, kt = idx >> 12;
    int k = 32 * kt + 8 * (lane >> 4) + j;
    int n = 16 * nt + (lane & 15);
    float w = Wb[k * 128 + n];
    unsigned short hi = f2bf(w);
    float lo = w - bf2f(hi);
    Wg[idx] = hi;
    Wg[16384 + idx] = f2bf(lo);
}

__global__ void relu_decode(unsigned* __restrict__ p, int n) {
    int i = blockIdx.x * blockDim.x + threadIdx.x;
    int stride = gridDim.x * blockDim.x;
    for (; i < n; i += stride) {
        float f = dec_f32(p[i]);
        ((float*)p)[i] = fmaxf(f, 0.0f);
    }
}

__global__ void out_decode(unsigned* __restrict__ p, int n) {
    int i = blockIdx.x * blockDim.x + threadIdx.x;
    int stride = gridDim.x * blockDim.x;
    for (; i < n; i += stride) {
        unsigned e = p[i];
        float f = (e == ENC_NEG_INF) ? 0.0f : dec_f32(e);
        ((float*)p)[i] = f;
    }
}

// ---------------- sort-by-dst (counting sort) ----------------

__global__ void hist_dst(const int* __restrict__ dst, unsigned* __restrict__ count) {
    int i = blockIdx.x * blockDim.x + threadIdx.x;
    if (i < N_EDGES) atomicAdd(&count[dst[i]], 1u);
}

__global__ __launch_bounds__(1024) void scan_offsets(const unsigned* __restrict__ count,
                                                     unsigned* __restrict__ cursor) {
    __shared__ unsigned sums[1024];
    const int PER = 49;
    int t = threadIdx.x;
    int base = t * PER;
    unsigned s = 0;
    for (int i = 0; i < PER; ++i) {
        int idx = base + i;
        if (idx < N_NODES) s += count[idx];
    }
    sums[t] = s;
    __syncthreads();
    for (int off = 1; off < 1024; off <<= 1) {
        unsigned v = (t >= off) ? sums[t - off] : 0u;
        __syncthreads();
        sums[t] += v;
        __syncthreads();
    }
    unsigned ex = sums[t] - s;
    for (int i = 0; i < PER; ++i) {
        int idx = base + i;
        if (idx < N_NODES) { cursor[idx] = ex; ex += count[idx]; }
    }
}

__global__ void scatter_edges(const int* __restrict__ src, const int* __restrict__ dst,
                              unsigned* __restrict__ cursor,
                              int* __restrict__ ssrc, int* __restrict__ sdst) {
    int i = blockIdx.x * blockDim.x + threadIdx.x;
    if (i < N_EDGES) {
        int d = dst[i];
        unsigned p = atomicAdd(&cursor[d], 1u);
        ssrc[p] = src[i];
        sdst[p] = d;
    }
}

// ---------------- node-level GEMM: C[M][256] = A[M][K] @ B[K][256] ----------------
__global__ __launch_bounds__(256) void gemm_uv(const float* __restrict__ A,
                                               const float* __restrict__ B,
                                               float* __restrict__ C,
                                               int M, int K) {
    __shared__ float As[16][64];
    __shared__ float Bs[16][64];
    int m0 = blockIdx.x * 64;
    int n0 = blockIdx.y * 64;
    int tid = threadIdx.x;
    int mg = tid & 15, ng = tid >> 4;
    float acc[4][4] = {};

    for (int kt = 0; kt < K; kt += 16) {
        {
            int m = tid >> 2, kq = tid & 3;
            float4 a = make_float4(0.f, 0.f, 0.f, 0.f);
            if (m0 + m < M) a = *(const float4*)&A[(size_t)(m0 + m) * K + kt + 4 * kq];
            As[4 * kq + 0][m] = a.x;
            As[4 * kq + 1][m] = a.y;
            As[4 * kq + 2][m] = a.z;
            As[4 * kq + 3][m] = a.w;
            int k = tid >> 4, nq = tid & 15;
            *(float4*)&Bs[k][4 * nq] = *(const float4*)&B[(size_t)(kt + k) * 256 + n0 + 4 * nq];
        }
        __syncthreads();
#pragma unroll
        for (int k = 0; k < 16; ++k) {
            float4 a = *(const float4*)&As[k][4 * mg];
            float4 b = *(const float4*)&Bs[k][4 * ng];
            float av[4] = {a.x, a.y, a.z, a.w};
            float bv[4] = {b.x, b.y, b.z, b.w};
#pragma unroll
            for (int i = 0; i < 4; ++i)
#pragma unroll
                for (int j = 0; j < 4; ++j)
                    acc[i][j] = fmaf(av[i], bv[j], acc[i][j]);
        }
        __syncthreads();
    }
#pragma unroll
    for (int i = 0; i < 4; ++i) {
        int m = m0 + 4 * mg + i;
        if (m < M) {
            float4 o = make_float4(acc[i][0], acc[i][1], acc[i][2], acc[i][3]);
            *(float4*)&C[(size_t)m * 256 + n0 + 4 * ng] = o;
        }
    }
}

// ---------------- MFMA edge MLP + segmented max-aggregate ----------------
// 128 sorted edges / block, 4 waves. A = bf16(T) built in regs from U/V gather,
// W = hi/lo planes streamed through one 32KB LDS buffer; M2 reduce in 64-col chunks.
__global__ __launch_bounds__(256, 4) void edge_mlp_mfma(
        const float* __restrict__ UV,          // [N][256]: U cols 0..127, V 128..255
        const float* __restrict__ ba,          // [128]
        const unsigned short* __restrict__ Wg, // frag layout, hi|lo, 32768 shorts
        const float* __restrict__ bb,          // [128]
        const int* __restrict__ ssrc,
        const int* __restrict__ sdst,
        unsigned* __restrict__ AGG) {          // [N][128] encoded
    __shared__ char lds[33792];                // union: W plane (32KB) | M2[128][66] f32 chunk
    __shared__ int sdst_s[128];
    int tid = threadIdx.x;
    int e0 = blockIdx.x * 128;
    int w = tid >> 6, l = tid & 63;
    int q = l >> 4, m = l & 15;

    if (tid < 128) sdst_s[tid] = sdst[e0 + tid];

    // stage W hi plane (32KB)
    {
        const float4* s4 = (const float4*)Wg;
        float4* d4 = (float4*)lds;
#pragma unroll
        for (int i = 0; i < 8; ++i) d4[tid + 256 * i] = s4[tid + 256 * i];
    }

    // build A fragments in registers (bf16 hi only)
    short8 ahi[2][4];
#pragma unroll
    for (int mt = 0; mt < 2; ++mt) {
        int e = e0 + 32 * w + 16 * mt + m;
        int d = sdst[e], s = ssrc[e];
        const float4* Ud = (const float4*)&UV[(size_t)d * 256];
        const float4* Vs = (const float4*)&UV[(size_t)s * 256 + 128];
#pragma unroll
        for (int kt = 0; kt < 4; ++kt) {
            float4 u0 = Ud[8 * kt + 2 * q], u1 = Ud[8 * kt + 2 * q + 1];
            float4 v0 = Vs[8 * kt + 2 * q], v1 = Vs[8 * kt + 2 * q + 1];
            float4 a0 = *(const float4*)&ba[32 * kt + 8 * q];
            float4 a1 = *(const float4*)&ba[32 * kt + 8 * q + 4];
            float t[8];
            t[0] = fmaxf(u0.x + v0.x + a0.x, 0.f);
            t[1] = fmaxf(u0.y + v0.y + a0.y, 0.f);
            t[2] = fmaxf(u0.z + v0.z + a0.z, 0.f);
            t[3] = fmaxf(u0.w + v0.w + a0.w, 0.f);
            t[4] = fmaxf(u1.x + v1.x + a1.x, 0.f);
            t[5] = fmaxf(u1.y + v1.y + a1.y, 0.f);
            t[6] = fmaxf(u1.z + v1.z + a1.z, 0.f);
            t[7] = fmaxf(u1.w + v1.w + a1.w, 0.f);
            short8 hi;
#pragma unroll
            for (int j = 0; j < 8; ++j) hi[j] = (short)f2bf(t[j]);
            ahi[mt][kt] = hi;
        }
    }

    f32x4 acc[2][8];
#pragma unroll
    for (int mt = 0; mt < 2; ++mt)
#pragma unroll
        for (int nt = 0; nt < 8; ++nt)
            acc[mt][nt] = (f32x4){0.f, 0.f, 0.f, 0.f};

    const short8* bfr = (const short8*)lds;    // [(kt*8+nt)*64 + lane]

    __syncthreads();   // Whi visible
#pragma unroll
    for (int nt = 0; nt < 8; ++nt)
#pragma unroll
        for (int kt = 0; kt < 4; ++kt) {
            short8 b = bfr[(kt * 8 + nt) * 64 + l];
            acc[0][nt] = __builtin_amdgcn_mfma_f32_16x16x32_bf16(ahi[0][kt], b, acc[0][nt], 0, 0, 0);
            acc[1][nt] = __builtin_amdgcn_mfma_f32_16x16x32_bf16(ahi[1][kt], b, acc[1][nt], 0, 0, 0);
        }
    __syncthreads();   // done reading Whi

    // stage W lo plane into same 32KB
    {
        const float4* s4 = ((const float4*)Wg) + 2048;
        float4* d4 = (float4*)lds;
#pragma unroll
        for (int i = 0; i < 8; ++i) d4[tid + 256 * i] = s4[tid + 256 * i];
    }
    __syncthreads();
#pragma unroll
    for (int nt = 0; nt < 8; ++nt)
#pragma unroll
        for (int kt = 0; kt < 4; ++kt) {
            short8 b = bfr[(kt * 8 + nt) * 64 + l];
            acc[0][nt] = __builtin_amdgcn_mfma_f32_16x16x32_bf16(ahi[0][kt], b, acc[0][nt], 0, 0, 0);
            acc[1][nt] = __builtin_amdgcn_mfma_f32_16x16x32_bf16(ahi[1][kt], b, acc[1][nt], 0, 0, 0);
        }
    __syncthreads();   // LDS free for M2

    // two 64-col chunks: deposit M2[e][c] (stride 66, 2-way banks = free), seg-max reduce
    float* M2 = (float*)lds;
#pragma unroll
    for (int ch = 0; ch < 2; ++ch) {
#pragma unroll
        for (int nt = 0; nt < 4; ++nt) {
            int nn = 4 * ch + nt;
            float bbv = bb[16 * nn + m];
#pragma unroll
            for (int mt = 0; mt < 2; ++mt)
#pragma unroll
                for (int r = 0; r < 4; ++r)
                    M2[(32 * w + 16 * mt + 4 * q + r) * 66 + 16 * nt + m] = acc[mt][nn][r] + bbv;
        }
        __syncthreads();
        {
            int c = tid & 63, h = tid >> 6;
            int eb = 32 * h;
            int cur = sdst_s[eb];
            float mx = -3.402823466e38f;
            for (int e = eb; e < eb + 32; ++e) {
                int de = sdst_s[e];
                if (de != cur) {
                    atomicMax(&AGG[(size_t)cur * 128 + 64 * ch + c], enc_f32(mx));
                    cur = de;
                    mx = -3.402823466e38f;
                }
                mx = fmaxf(mx, M2[e * 66 + c]);
            }
            atomicMax(&AGG[(size_t)cur * 128 + 64 * ch + c], enc_f32(mx));
        }
        __syncthreads();
    }
}

// ---------------- launch ----------------

extern "C" void kernel_launch(void* const* d_in, const int* in_sizes, int n_in,
                              void* d_out, int out_size, void* d_ws, size_t ws_size,
                              hipStream_t stream) {
    const float* x   = (const float*)d_in[0];
    const int*   ei  = (const int*)d_in[1];
    const float* W1a = (const float*)d_in[2];
    const float* b1a = (const float*)d_in[3];
    const float* W1b = (const float*)d_in[4];
    const float* b1b = (const float*)d_in[5];
    const float* W2a = (const float*)d_in[6];
    const float* b2a = (const float*)d_in[7];
    const float* W2b = (const float*)d_in[8];
    const float* b2b = (const float*)d_in[9];
    const int* src = ei;
    const int* dst = ei + N_EDGES;

    char* ws = (char*)d_ws;
    float*          UV    = (float*)ws;                          // 51.2 MB
    unsigned*       AGG1  = (unsigned*)(ws + 51200000);          // 25.6 MB
    float*          WC1   = (float*)(ws + 76800000);             // 64 KB
    float*          WC2   = (float*)(ws + 76865536);             // 128 KB
    int*            ssrc  = (int*)(ws + 76996608);               // 3.2 MB
    int*            sdst  = (int*)(ws + 80196608);               // 3.2 MB
    unsigned*       count = (unsigned*)(ws + 83396608);          // 200 KB
    unsigned*       cursor= (unsigned*)(ws + 83596608);          // 200 KB
    unsigned short* Wg1   = (unsigned short*)(ws + 83796608);    // 64 KB
    unsigned short* Wg2   = (unsigned short*)(ws + 83862144);    // 64 KB

    const int NH = N_NODES * HID;   // 6.4M

    prep_wcat<<<64, 256, 0, stream>>>(W1a, 64, WC1);
    prep_wcat<<<128, 256, 0, stream>>>(W2a, 128, WC2);
    prep_wfrag<<<64, 256, 0, stream>>>(W1b, Wg1);
    prep_wfrag<<<64, 256, 0, stream>>>(W2b, Wg2);
    fill_u32<<<2048, 256, 0, stream>>>(AGG1, NH, ENC_NEG_INF);
    fill_u32<<<2048, 256, 0, stream>>>((unsigned*)d_out, NH, ENC_NEG_INF);
    fill_u32<<<196, 256, 0, stream>>>(count, N_NODES, 0u);

    // counting sort of edges by dst (max is order-independent -> deterministic)
    hist_dst<<<3125, 256, 0, stream>>>(dst, count);
    scan_offsets<<<1, 1024, 0, stream>>>(count, cursor);
    scatter_edges<<<3125, 256, 0, stream>>>(src, dst, cursor, ssrc, sdst);

    // Layer 1
    gemm_uv<<<dim3(782, 4), 256, 0, stream>>>(x, WC1, UV, N_NODES, 64);
    edge_mlp_mfma<<<N_EDGES / 128, 256, 0, stream>>>(UV, b1a, Wg1, b1b, ssrc, sdst, AGG1);
    relu_decode<<<2048, 256, 0, stream>>>(AGG1, NH);

    // Layer 2
    gemm_uv<<<dim3(782, 4), 256, 0, stream>>>((const float*)AGG1, WC2, UV, N_NODES, 128);
    edge_mlp_mfma<<<N_EDGES / 128, 256, 0, stream>>>(UV, b2a, Wg2, b2b, ssrc, sdst, (unsigned*)d_out);
    out_decode<<<2048, 256, 0, stream>>>((unsigned*)d_out, NH);
}

// Round 5
// 457.085 us; speedup vs baseline: 9.8677x; 1.0665x over previous
//
#include <hip/hip_runtime.h>
#include <stdint.h>

#define N_NODES 50000
#define N_EDGES 800000
#define HID 128
#define NWG_E (N_EDGES / 128)      // 6250 edge blocks
#define XQ (NWG_E / 8)             // 781
#define XR (NWG_E % 8)             // 2

#define ENC_NEG_INF 0x007FFFFFu   // enc(-inf)

typedef short short8 __attribute__((ext_vector_type(8)));
typedef float f32x4 __attribute__((ext_vector_type(4)));

__device__ __forceinline__ unsigned enc_f32(float f) {
    unsigned u = __float_as_uint(f);
    return (u & 0x80000000u) ? ~u : (u | 0x80000000u);
}
__device__ __forceinline__ float dec_f32(unsigned e) {
    unsigned u = (e & 0x80000000u) ? (e & 0x7FFFFFFFu) : ~e;
    return __uint_as_float(u);
}
__device__ __forceinline__ unsigned short f2bf(float f) {
    unsigned u = __float_as_uint(f);
    unsigned r = (u + 0x7fffu + ((u >> 16) & 1u)) >> 16;
    return (unsigned short)r;
}
__device__ __forceinline__ float bf2f(unsigned short h) {
    return __uint_as_float(((unsigned)h) << 16);
}

// ---------------- utility kernels ----------------

__global__ void fill_u32(unsigned* __restrict__ p, int n, unsigned v) {
    int i = blockIdx.x * blockDim.x + threadIdx.x;
    int stride = gridDim.x * blockDim.x;
    for (; i < n; i += stride) p[i] = v;
}

// Build combined weight WC[K][256]: cols 0..127 = Wtop - Wbot, 128..255 = Wbot
__global__ void prep_wcat(const float* __restrict__ W, int K, float* __restrict__ WC) {
    int idx = blockIdx.x * 256 + threadIdx.x;
    if (idx >= K * 256) return;
    int k = idx >> 8, c = idx & 255;
    float v;
    if (c < 128) v = W[k * 128 + c] - W[(k + K) * 128 + c];
    else         v = W[(k + K) * 128 + (c - 128)];
    WC[idx] = v;
}

// Wb[128][128] -> MFMA B-fragment layout, hi plane then lo plane (16384 shorts each)
__global__ void prep_wfrag(const float* __restrict__ Wb, unsigned short* __restrict__ Wg) {
    int idx = blockIdx.x * 256 + threadIdx.x;   // 0..16383
    int j = idx & 7, lane = (idx >> 3) & 63, nt = (idx >> 9) & 7, kt = idx >> 12;
    int k = 32 * kt + 8 * (lane >> 4) + j;
    int n = 16 * nt + (lane & 15);
    float w = Wb[k * 128 + n];
    unsigned short hi = f2bf(w);
    float lo = w - bf2f(hi);
    Wg[idx] = hi;
    Wg[16384 + idx] = f2bf(lo);
}

__global__ void out_decode(unsigned* __restrict__ p, int n) {
    int i = blockIdx.x * blockDim.x + threadIdx.x;
    int stride = gridDim.x * blockDim.x;
    for (; i < n; i += stride) {
        unsigned e = p[i];
        float f = (e == ENC_NEG_INF) ? 0.0f : dec_f32(e);
        ((float*)p)[i] = f;
    }
}

// ---------------- sort-by-dst (counting sort) ----------------

__global__ void hist_dst(const int* __restrict__ dst, unsigned* __restrict__ count) {
    int i = blockIdx.x * blockDim.x + threadIdx.x;
    if (i < N_EDGES) atomicAdd(&count[dst[i]], 1u);
}

__global__ __launch_bounds__(1024) void scan_offsets(const unsigned* __restrict__ count,
                                                     unsigned* __restrict__ cursor) {
    __shared__ unsigned sums[1024];
    const int PER = 49;
    int t = threadIdx.x;
    int base = t * PER;
    unsigned s = 0;
    for (int i = 0; i < PER; ++i) {
        int idx = base + i;
        if (idx < N_NODES) s += count[idx];
    }
    sums[t] = s;
    __syncthreads();
    for (int off = 1; off < 1024; off <<= 1) {
        unsigned v = (t >= off) ? sums[t - off] : 0u;
        __syncthreads();
        sums[t] += v;
        __syncthreads();
    }
    unsigned ex = sums[t] - s;
    for (int i = 0; i < PER; ++i) {
        int idx = base + i;
        if (idx < N_NODES) { cursor[idx] = ex; ex += count[idx]; }
    }
}

__global__ void scatter_edges(const int* __restrict__ src, const int* __restrict__ dst,
                              unsigned* __restrict__ cursor,
                              int* __restrict__ ssrc, int* __restrict__ sdst) {
    int i = blockIdx.x * blockDim.x + threadIdx.x;
    if (i < N_EDGES) {
        int d = dst[i];
        unsigned p = atomicAdd(&cursor[d], 1u);
        ssrc[p] = src[i];
        sdst[p] = d;
    }
}

// ---------------- node-level GEMM: C[M][256](bf16) = op(A)[M][K] @ B[K][256] ----------------
// DEC=0: A is plain f32.  DEC=1: A is encoded u32, op = relu(decode) (fuses relu_decode).
template<int DEC>
__global__ __launch_bounds__(256) void gemm_uv(const void* __restrict__ A_,
                                               const float* __restrict__ B,
                                               unsigned short* __restrict__ C,
                                               int M, int K) {
    __shared__ float As[16][64];
    __shared__ float Bs[16][64];
    int m0 = blockIdx.x * 64;
    int n0 = blockIdx.y * 64;
    int tid = threadIdx.x;
    int mg = tid & 15, ng = tid >> 4;
    float acc[4][4] = {};

    for (int kt = 0; kt < K; kt += 16) {
        {
            int m = tid >> 2, kq = tid & 3;
            float av[4] = {0.f, 0.f, 0.f, 0.f};
            if (m0 + m < M) {
                if (DEC) {
                    uint4 r = *(const uint4*)&((const unsigned*)A_)[(size_t)(m0 + m) * K + kt + 4 * kq];
                    av[0] = fmaxf(dec_f32(r.x), 0.f);
                    av[1] = fmaxf(dec_f32(r.y), 0.f);
                    av[2] = fmaxf(dec_f32(r.z), 0.f);
                    av[3] = fmaxf(dec_f32(r.w), 0.f);
                } else {
                    float4 a = *(const float4*)&((const float*)A_)[(size_t)(m0 + m) * K + kt + 4 * kq];
                    av[0] = a.x; av[1] = a.y; av[2] = a.z; av[3] = a.w;
                }
            }
            As[4 * kq + 0][m] = av[0];
            As[4 * kq + 1][m] = av[1];
            As[4 * kq + 2][m] = av[2];
            As[4 * kq + 3][m] = av[3];
            int k = tid >> 4, nq = tid & 15;
            *(float4*)&Bs[k][4 * nq] = *(const float4*)&B[(size_t)(kt + k) * 256 + n0 + 4 * nq];
        }
        __syncthreads();
#pragma unroll
        for (int k = 0; k < 16; ++k) {
            float4 a = *(const float4*)&As[k][4 * mg];
            float4 b = *(const float4*)&Bs[k][4 * ng];
            float av[4] = {a.x, a.y, a.z, a.w};
            float bv[4] = {b.x, b.y, b.z, b.w};
#pragma unroll
            for (int i = 0; i < 4; ++i)
#pragma unroll
                for (int j = 0; j < 4; ++j)
                    acc[i][j] = fmaf(av[i], bv[j], acc[i][j]);
        }
        __syncthreads();
    }
#pragma unroll
    for (int i = 0; i < 4; ++i) {
        int m = m0 + 4 * mg + i;
        if (m < M) {
            unsigned lo = (unsigned)f2bf(acc[i][0]) | ((unsigned)f2bf(acc[i][1]) << 16);
            unsigned hi = (unsigned)f2bf(acc[i][2]) | ((unsigned)f2bf(acc[i][3]) << 16);
            uint2 o = make_uint2(lo, hi);
            *(uint2*)&C[(size_t)m * 256 + n0 + 4 * ng] = o;
        }
    }
}

// ---------------- MFMA edge MLP + segmented max-aggregate ----------------
// 128 sorted edges / block, 4 waves. UV is bf16 [N][256]. XCD-swizzled blocks.
__global__ __launch_bounds__(256, 4) void edge_mlp_mfma(
        const unsigned short* __restrict__ UV, // [N][256] bf16: U 0..127, V 128..255
        const float* __restrict__ ba,          // [128]
        const unsigned short* __restrict__ Wg, // frag layout, hi|lo, 32768 shorts
        const float* __restrict__ bb,          // [128]
        const int* __restrict__ ssrc,
        const int* __restrict__ sdst,
        unsigned* __restrict__ AGG) {          // [N][128] encoded
    __shared__ char lds[33792];                // union: W plane (32KB) | M2[128][66] f32 chunk
    __shared__ int sdst_s[128];
    int tid = threadIdx.x;
    // bijective XCD-chunked swizzle: consecutive sorted-edge chunks stay on one XCD
    int orig = blockIdx.x;
    int xcd = orig & 7, ii = orig >> 3;
    int wg = (xcd < XR) ? xcd * (XQ + 1) + ii : XR * (XQ + 1) + (xcd - XR) * XQ + ii;
    int e0 = wg * 128;
    int w = tid >> 6, l = tid & 63;
    int q = l >> 4, m = l & 15;

    if (tid < 128) sdst_s[tid] = sdst[e0 + tid];

    // stage W hi plane (32KB)
    {
        const float4* s4 = (const float4*)Wg;
        float4* d4 = (float4*)lds;
#pragma unroll
        for (int i = 0; i < 8; ++i) d4[tid + 256 * i] = s4[tid + 256 * i];
    }

    // build A fragments in registers (bf16): t = relu(u + v + ba)
    short8 ahi[2][4];
#pragma unroll
    for (int mt = 0; mt < 2; ++mt) {
        int e = e0 + 32 * w + 16 * mt + m;
        int d = sdst[e], s = ssrc[e];
        const short8* Ud = (const short8*)&UV[(size_t)d * 256];
        const short8* Vs = (const short8*)&UV[(size_t)s * 256 + 128];
#pragma unroll
        for (int kt = 0; kt < 4; ++kt) {
            short8 u8 = Ud[4 * kt + q];
            short8 v8 = Vs[4 * kt + q];
            float4 a0 = *(const float4*)&ba[32 * kt + 8 * q];
            float4 a1 = *(const float4*)&ba[32 * kt + 8 * q + 4];
            float bav[8] = {a0.x, a0.y, a0.z, a0.w, a1.x, a1.y, a1.z, a1.w};
            short8 hi;
#pragma unroll
            for (int j = 0; j < 8; ++j) {
                float t = bf2f((unsigned short)u8[j]) + bf2f((unsigned short)v8[j]) + bav[j];
                hi[j] = (short)f2bf(fmaxf(t, 0.f));
            }
            ahi[mt][kt] = hi;
        }
    }

    f32x4 acc[2][8];
#pragma unroll
    for (int mt = 0; mt < 2; ++mt)
#pragma unroll
        for (int nt = 0; nt < 8; ++nt)
            acc[mt][nt] = (f32x4){0.f, 0.f, 0.f, 0.f};

    const short8* bfr = (const short8*)lds;    // [(kt*8+nt)*64 + lane]

    __syncthreads();   // Whi visible
#pragma unroll
    for (int nt = 0; nt < 8; ++nt)
#pragma unroll
        for (int kt = 0; kt < 4; ++kt) {
            short8 b = bfr[(kt * 8 + nt) * 64 + l];
            acc[0][nt] = __builtin_amdgcn_mfma_f32_16x16x32_bf16(ahi[0][kt], b, acc[0][nt], 0, 0, 0);
            acc[1][nt] = __builtin_amdgcn_mfma_f32_16x16x32_bf16(ahi[1][kt], b, acc[1][nt], 0, 0, 0);
        }
    __syncthreads();   // done reading Whi

    // stage W lo plane into same 32KB
    {
        const float4* s4 = ((const float4*)Wg) + 2048;
        float4* d4 = (float4*)lds;
#pragma unroll
        for (int i = 0; i < 8; ++i) d4[tid + 256 * i] = s4[tid + 256 * i];
    }
    __syncthreads();
#pragma unroll
    for (int nt = 0; nt < 8; ++nt)
#pragma unroll
        for (int kt = 0; kt < 4; ++kt) {
            short8 b = bfr[(kt * 8 + nt) * 64 + l];
            acc[0][nt] = __builtin_amdgcn_mfma_f32_16x16x32_bf16(ahi[0][kt], b, acc[0][nt], 0, 0, 0);
            acc[1][nt] = __builtin_amdgcn_mfma_f32_16x16x32_bf16(ahi[1][kt], b, acc[1][nt], 0, 0, 0);
        }
    __syncthreads();   // LDS free for M2

    // two 64-col chunks: deposit M2[e][c] (stride 66), seg-max reduce
    float* M2 = (float*)lds;
#pragma unroll
    for (int ch = 0; ch < 2; ++ch) {
#pragma unroll
        for (int nt = 0; nt < 4; ++nt) {
            int nn = 4 * ch + nt;
            float bbv = bb[16 * nn + m];
#pragma unroll
            for (int mt = 0; mt < 2; ++mt)
#pragma unroll
                for (int r = 0; r < 4; ++r)
                    M2[(32 * w + 16 * mt + 4 * q + r) * 66 + 16 * nt + m] = acc[mt][nn][r] + bbv;
        }
        __syncthreads();
        {
            int c = tid & 63, h = tid >> 6;
            int eb = 32 * h;
            int cur = sdst_s[eb];
            float mx = -3.402823466e38f;
            for (int e = eb; e < eb + 32; ++e) {
                int de = sdst_s[e];
                if (de != cur) {
                    atomicMax(&AGG[(size_t)cur * 128 + 64 * ch + c], enc_f32(mx));
                    cur = de;
                    mx = -3.402823466e38f;
                }
                mx = fmaxf(mx, M2[e * 66 + c]);
            }
            atomicMax(&AGG[(size_t)cur * 128 + 64 * ch + c], enc_f32(mx));
        }
        __syncthreads();
    }
}

// ---------------- launch ----------------

extern "C" void kernel_launch(void* const* d_in, const int* in_sizes, int n_in,
                              void* d_out, int out_size, void* d_ws, size_t ws_size,
                              hipStream_t stream) {
    const float* x   = (const float*)d_in[0];
    const int*   ei  = (const int*)d_in[1];
    const float* W1a = (const float*)d_in[2];
    const float* b1a = (const float*)d_in[3];
    const float* W1b = (const float*)d_in[4];
    const float* b1b = (const float*)d_in[5];
    const float* W2a = (const float*)d_in[6];
    const float* b2a = (const float*)d_in[7];
    const float* W2b = (const float*)d_in[8];
    const float* b2b = (const float*)d_in[9];
    const int* src = ei;
    const int* dst = ei + N_EDGES;

    char* ws = (char*)d_ws;
    unsigned short* UV    = (unsigned short*)ws;                 // 25.6 MB (bf16)
    unsigned*       AGG1  = (unsigned*)(ws + 25600000);          // 25.6 MB
    float*          WC1   = (float*)(ws + 51200000);             // 64 KB
    float*          WC2   = (float*)(ws + 51265536);             // 128 KB
    int*            ssrc  = (int*)(ws + 51396608);               // 3.2 MB
    int*            sdst  = (int*)(ws + 54596608);               // 3.2 MB
    unsigned*       count = (unsigned*)(ws + 57796608);          // 200 KB
    unsigned*       cursor= (unsigned*)(ws + 57996608);          // 200 KB
    unsigned short* Wg1   = (unsigned short*)(ws + 58196608);    // 64 KB
    unsigned short* Wg2   = (unsigned short*)(ws + 58262144);    // 64 KB

    const int NH = N_NODES * HID;   // 6.4M

    prep_wcat<<<64, 256, 0, stream>>>(W1a, 64, WC1);
    prep_wcat<<<128, 256, 0, stream>>>(W2a, 128, WC2);
    prep_wfrag<<<64, 256, 0, stream>>>(W1b, Wg1);
    prep_wfrag<<<64, 256, 0, stream>>>(W2b, Wg2);
    fill_u32<<<2048, 256, 0, stream>>>(AGG1, NH, ENC_NEG_INF);
    fill_u32<<<2048, 256, 0, stream>>>((unsigned*)d_out, NH, ENC_NEG_INF);
    fill_u32<<<196, 256, 0, stream>>>(count, N_NODES, 0u);

    // counting sort of edges by dst (max is order-independent -> deterministic)
    hist_dst<<<3125, 256, 0, stream>>>(dst, count);
    scan_offsets<<<1, 1024, 0, stream>>>(count, cursor);
    scatter_edges<<<3125, 256, 0, stream>>>(src, dst, cursor, ssrc, sdst);

    // Layer 1
    gemm_uv<0><<<dim3(782, 4), 256, 0, stream>>>(x, WC1, UV, N_NODES, 64);
    edge_mlp_mfma<<<NWG_E, 256, 0, stream>>>(UV, b1a, Wg1, b1b, ssrc, sdst, AGG1);

    // Layer 2 (relu of AGG1 fused into A-load)
    gemm_uv<1><<<dim3(782, 4), 256, 0, stream>>>(AGG1, WC2, UV, N_NODES, 128);
    edge_mlp_mfma<<<NWG_E, 256, 0, stream>>>(UV, b2a, Wg2, b2b, ssrc, sdst, (unsigned*)d_out);
    out_decode<<<2048, 256, 0, stream>>>((unsigned*)d_out, NH);
}

// Round 6
// 398.547 us; speedup vs baseline: 11.3171x; 1.1469x over previous
//
#include <hip/hip_runtime.h>
#include <stdint.h>

#define N_NODES 50000
#define N_EDGES 800000
#define HID 128
#define NWG_E (N_EDGES / 128)      // 6250 edge blocks
#define XQ (NWG_E / 8)             // 781
#define XR (NWG_E % 8)             // 2

#define ENC_NEG_INF 0x007FFFFFu   // enc(-inf)

typedef short short8 __attribute__((ext_vector_type(8)));
typedef float f32x4 __attribute__((ext_vector_type(4)));

__device__ __forceinline__ unsigned enc_f32(float f) {
    unsigned u = __float_as_uint(f);
    return (u & 0x80000000u) ? ~u : (u | 0x80000000u);
}
__device__ __forceinline__ float dec_f32(unsigned e) {
    unsigned u = (e & 0x80000000u) ? (e & 0x7FFFFFFFu) : ~e;
    return __uint_as_float(u);
}
__device__ __forceinline__ unsigned short f2bf(float f) {
    unsigned u = __float_as_uint(f);
    unsigned r = (u + 0x7fffu + ((u >> 16) & 1u)) >> 16;
    return (unsigned short)r;
}
__device__ __forceinline__ float bf2f(unsigned short h) {
    return __uint_as_float(((unsigned)h) << 16);
}

// ---------------- utility kernels ----------------

__global__ void fill_u32(unsigned* __restrict__ p, int n, unsigned v) {
    int i = blockIdx.x * blockDim.x + threadIdx.x;
    int stride = gridDim.x * blockDim.x;
    for (; i < n; i += stride) p[i] = v;
}

// Build combined weight WC[K][256]: cols 0..127 = Wtop - Wbot, 128..255 = Wbot
__global__ void prep_wcat(const float* __restrict__ W, int K, float* __restrict__ WC) {
    int idx = blockIdx.x * 256 + threadIdx.x;
    if (idx >= K * 256) return;
    int k = idx >> 8, c = idx & 255;
    float v;
    if (c < 128) v = W[k * 128 + c] - W[(k + K) * 128 + c];
    else         v = W[(k + K) * 128 + (c - 128)];
    WC[idx] = v;
}

// Wb[128][128] -> MFMA B-frag layout (N=128, 8 n-tiles), hi|lo planes of 16384 shorts
__global__ void prep_wfrag(const float* __restrict__ Wb, unsigned short* __restrict__ Wg) {
    int idx = blockIdx.x * 256 + threadIdx.x;   // 0..16383
    int j = idx & 7, lane = (idx >> 3) & 63, nt = (idx >> 9) & 7, kt = idx >> 12;
    int k = 32 * kt + 8 * (lane >> 4) + j;
    int n = 16 * nt + (lane & 15);
    float w = Wb[k * 128 + n];
    unsigned short hi = f2bf(w);
    Wg[idx] = hi;
    Wg[16384 + idx] = f2bf(w - bf2f(hi));
}

// WC[K][256] -> MFMA B-frag layout (N=256, 16 n-tiles), hi plane then lo plane (K*256 each)
__global__ void prep_wfrag256(const float* __restrict__ WC, int K, unsigned short* __restrict__ Wg) {
    int idx = blockIdx.x * 256 + threadIdx.x;
    if (idx >= K * 256) return;
    int j = idx & 7, l = (idx >> 3) & 63, nt = (idx >> 9) & 15, kt = idx >> 13;
    int k = 32 * kt + 8 * (l >> 4) + j;
    int n = 16 * nt + (l & 15);
    float v = WC[k * 256 + n];
    unsigned short hi = f2bf(v);
    Wg[idx] = hi;
    Wg[K * 256 + idx] = f2bf(v - bf2f(hi));
}

// final: encoded u32 -> decoded float + bias; empty segment -> 0
__global__ void out_decode(unsigned* __restrict__ p, const float* __restrict__ bias, int n) {
    int i = blockIdx.x * blockDim.x + threadIdx.x;
    int stride = gridDim.x * blockDim.x;
    for (; i < n; i += stride) {
        unsigned e = p[i];
        float f = (e == ENC_NEG_INF) ? 0.0f : dec_f32(e) + bias[i & 127];
        ((float*)p)[i] = f;
    }
}

// ---------------- sort-by-dst (counting sort) ----------------

__global__ void hist_dst(const int* __restrict__ dst, unsigned* __restrict__ count) {
    int i = blockIdx.x * blockDim.x + threadIdx.x;
    if (i < N_EDGES) atomicAdd(&count[dst[i]], 1u);
}

__global__ __launch_bounds__(1024) void scan_offsets(const unsigned* __restrict__ count,
                                                     unsigned* __restrict__ cursor) {
    __shared__ unsigned sums[1024];
    const int PER = 49;
    int t = threadIdx.x;
    int base = t * PER;
    unsigned s = 0;
    for (int i = 0; i < PER; ++i) {
        int idx = base + i;
        if (idx < N_NODES) s += count[idx];
    }
    sums[t] = s;
    __syncthreads();
    for (int off = 1; off < 1024; off <<= 1) {
        unsigned v = (t >= off) ? sums[t - off] : 0u;
        __syncthreads();
        sums[t] += v;
        __syncthreads();
    }
    unsigned ex = sums[t] - s;
    for (int i = 0; i < PER; ++i) {
        int idx = base + i;
        if (idx < N_NODES) { cursor[idx] = ex; ex += count[idx]; }
    }
}

__global__ void scatter_edges(const int* __restrict__ src, const int* __restrict__ dst,
                              unsigned* __restrict__ cursor,
                              int* __restrict__ ssrc, int* __restrict__ sdst) {
    int i = blockIdx.x * blockDim.x + threadIdx.x;
    if (i < N_EDGES) {
        int d = dst[i];
        unsigned p = atomicAdd(&cursor[d], 1u);
        ssrc[p] = src[i];
        sdst[p] = d;
    }
}

// ---------------- MFMA node GEMM: C[M][256](bf16) = op(A)[M][K] @ WC[K][256] ----------------
// DEC=0: A f32.  DEC=1: A encoded u32, op = relu(decode + bprev).
// W hi+lo planes (frag layout) streamed via LDS; U-bias bu added to cols of by==0.
template<int DEC, int KT>
__global__ __launch_bounds__(256, 2) void gemm_uv_mfma(
        const void* __restrict__ A_,
        const unsigned short* __restrict__ Wg,   // frag layout, hi|lo planes (K*256 shorts each)
        const float* __restrict__ bprev,         // DEC=1 bias (pre-relu); unused otherwise
        const float* __restrict__ bu,            // U-col bias, applied when by==0
        unsigned short* __restrict__ C,          // [M][256] bf16
        int M) {
    __shared__ char lds[KT * 8192];              // one plane-portion: KT x 8 tiles x 1KB
    const int K = 32 * KT;
    int tid = threadIdx.x;
    int bx = blockIdx.x, by = blockIdx.y;
    int r0 = bx * 128;
    int w = tid >> 6, l = tid & 63;
    int q = l >> 4, m = l & 15;

    // A fragments (bf16 hi)
    short8 ahi[2][KT];
#pragma unroll
    for (int mt = 0; mt < 2; ++mt) {
        int row = r0 + 32 * w + 16 * mt + m;
        bool ok = row < M;
#pragma unroll
        for (int kt = 0; kt < KT; ++kt) {
            float av[8] = {0.f, 0.f, 0.f, 0.f, 0.f, 0.f, 0.f, 0.f};
            if (ok) {
                if (DEC) {
                    const unsigned* Ar = (const unsigned*)A_ + (size_t)row * K + 32 * kt + 8 * q;
                    uint4 x0 = *(const uint4*)Ar;
                    uint4 x1 = *(const uint4*)(Ar + 4);
                    float4 g0 = *(const float4*)&bprev[32 * kt + 8 * q];
                    float4 g1 = *(const float4*)&bprev[32 * kt + 8 * q + 4];
                    av[0] = fmaxf(dec_f32(x0.x) + g0.x, 0.f);
                    av[1] = fmaxf(dec_f32(x0.y) + g0.y, 0.f);
                    av[2] = fmaxf(dec_f32(x0.z) + g0.z, 0.f);
                    av[3] = fmaxf(dec_f32(x0.w) + g0.w, 0.f);
                    av[4] = fmaxf(dec_f32(x1.x) + g1.x, 0.f);
                    av[5] = fmaxf(dec_f32(x1.y) + g1.y, 0.f);
                    av[6] = fmaxf(dec_f32(x1.z) + g1.z, 0.f);
                    av[7] = fmaxf(dec_f32(x1.w) + g1.w, 0.f);
                } else {
                    const float* Ar = (const float*)A_ + (size_t)row * K + 32 * kt + 8 * q;
                    float4 f0 = *(const float4*)Ar;
                    float4 f1 = *(const float4*)(Ar + 4);
                    av[0] = f0.x; av[1] = f0.y; av[2] = f0.z; av[3] = f0.w;
                    av[4] = f1.x; av[5] = f1.y; av[6] = f1.z; av[7] = f1.w;
                }
            }
            short8 hi;
#pragma unroll
            for (int j = 0; j < 8; ++j) hi[j] = (short)f2bf(av[j]);
            ahi[mt][kt] = hi;
        }
    }

    f32x4 acc[2][8];
#pragma unroll
    for (int mt = 0; mt < 2; ++mt)
#pragma unroll
        for (int nt = 0; nt < 8; ++nt)
            acc[mt][nt] = (f32x4){0.f, 0.f, 0.f, 0.f};

    const short8* bfr = (const short8*)lds;

    // two passes: hi plane, then lo plane
#pragma unroll
    for (int pl = 0; pl < 2; ++pl) {
        if (pl) __syncthreads();   // previous readers done
        {
            const float4* s4 = (const float4*)Wg + (size_t)pl * (K * 32);  // plane = K*32 float4
            float4* d4 = (float4*)lds;
#pragma unroll
            for (int it = 0; it < 2 * KT; ++it) {
                int f = 256 * it + tid;
                int tl = f >> 6, fin = f & 63;
                int tg = (tl >> 3) * 16 + 8 * by + (tl & 7);
                d4[f] = s4[tg * 64 + fin];
            }
        }
        __syncthreads();
#pragma unroll
        for (int nt = 0; nt < 8; ++nt)
#pragma unroll
            for (int kt = 0; kt < KT; ++kt) {
                short8 b = bfr[(kt * 8 + nt) * 64 + l];
                acc[0][nt] = __builtin_amdgcn_mfma_f32_16x16x32_bf16(ahi[0][kt], b, acc[0][nt], 0, 0, 0);
                acc[1][nt] = __builtin_amdgcn_mfma_f32_16x16x32_bf16(ahi[1][kt], b, acc[1][nt], 0, 0, 0);
            }
    }

    // epilogue: C[row][128*by + 16nt + m] (D: col=16nt+m, row=4q+r in m-tile)
#pragma unroll
    for (int nt = 0; nt < 8; ++nt) {
        float bias = (by == 0) ? bu[16 * nt + m] : 0.f;
#pragma unroll
        for (int mt = 0; mt < 2; ++mt) {
            int rowb = r0 + 32 * w + 16 * mt + 4 * q;
#pragma unroll
            for (int r = 0; r < 4; ++r) {
                int row = rowb + r;
                if (row < M)
                    C[(size_t)row * 256 + 128 * by + 16 * nt + m] = f2bf(acc[mt][nt][r] + bias);
            }
        }
    }
}

// ---------------- MFMA edge MLP + segmented max-aggregate ----------------
// 128 sorted edges / block, 4 waves. UV bf16 (biases pre-folded into U).
// T = relu(u+v); M = T @ Wb (hi plane only); seg-max -> atomicMax per run.
__global__ __launch_bounds__(256, 4) void edge_mlp_mfma(
        const unsigned short* __restrict__ UV, // [N][256] bf16: U 0..127 (incl. ba), V 128..255
        const unsigned short* __restrict__ Wg, // frag layout, hi plane first (16384 shorts)
        const int* __restrict__ ssrc,
        const int* __restrict__ sdst,
        unsigned* __restrict__ AGG) {          // [N][128] encoded (bb added downstream)
    __shared__ char lds[33792];                // union: Whi (32KB) | M2[128][66] f32 chunk
    __shared__ int sdst_s[128];
    int tid = threadIdx.x;
    // bijective XCD-chunked swizzle
    int orig = blockIdx.x;
    int xcd = orig & 7, ii = orig >> 3;
    int wg = (xcd < XR) ? xcd * (XQ + 1) + ii : XR * (XQ + 1) + (xcd - XR) * XQ + ii;
    int e0 = wg * 128;
    int w = tid >> 6, l = tid & 63;
    int q = l >> 4, m = l & 15;

    if (tid < 128) sdst_s[tid] = sdst[e0 + tid];

    // stage W hi plane (32KB)
    {
        const float4* s4 = (const float4*)Wg;
        float4* d4 = (float4*)lds;
#pragma unroll
        for (int i = 0; i < 8; ++i) d4[tid + 256 * i] = s4[tid + 256 * i];
    }

    // build A fragments: t = relu(u + v)
    short8 ahi[2][4];
#pragma unroll
    for (int mt = 0; mt < 2; ++mt) {
        int e = e0 + 32 * w + 16 * mt + m;
        int d = sdst[e], s = ssrc[e];
        const short8* Ud = (const short8*)&UV[(size_t)d * 256];
        const short8* Vs = (const short8*)&UV[(size_t)s * 256 + 128];
#pragma unroll
        for (int kt = 0; kt < 4; ++kt) {
            short8 u8 = Ud[4 * kt + q];
            short8 v8 = Vs[4 * kt + q];
            short8 hi;
#pragma unroll
            for (int j = 0; j < 8; ++j) {
                float t = bf2f((unsigned short)u8[j]) + bf2f((unsigned short)v8[j]);
                hi[j] = (short)f2bf(fmaxf(t, 0.f));
            }
            ahi[mt][kt] = hi;
        }
    }

    f32x4 acc[2][8];
#pragma unroll
    for (int mt = 0; mt < 2; ++mt)
#pragma unroll
        for (int nt = 0; nt < 8; ++nt)
            acc[mt][nt] = (f32x4){0.f, 0.f, 0.f, 0.f};

    const short8* bfr = (const short8*)lds;    // [(kt*8+nt)*64 + lane]

    __syncthreads();   // Whi visible
#pragma unroll
    for (int nt = 0; nt < 8; ++nt)
#pragma unroll
        for (int kt = 0; kt < 4; ++kt) {
            short8 b = bfr[(kt * 8 + nt) * 64 + l];
            acc[0][nt] = __builtin_amdgcn_mfma_f32_16x16x32_bf16(ahi[0][kt], b, acc[0][nt], 0, 0, 0);
            acc[1][nt] = __builtin_amdgcn_mfma_f32_16x16x32_bf16(ahi[1][kt], b, acc[1][nt], 0, 0, 0);
        }
    __syncthreads();   // done reading Whi; LDS free for M2

    // two 64-col chunks: deposit M2[e][c] (stride 66), seg-max reduce
    float* M2 = (float*)lds;
#pragma unroll
    for (int ch = 0; ch < 2; ++ch) {
#pragma unroll
        for (int nt = 0; nt < 4; ++nt) {
            int nn = 4 * ch + nt;
#pragma unroll
            for (int mt = 0; mt < 2; ++mt)
#pragma unroll
                for (int r = 0; r < 4; ++r)
                    M2[(32 * w + 16 * mt + 4 * q + r) * 66 + 16 * nt + m] = acc[mt][nn][r];
        }
        __syncthreads();
        {
            int c = tid & 63, h = tid >> 6;
            int eb = 32 * h;
            int cur = sdst_s[eb];
            float mx = -3.402823466e38f;
            for (int e = eb; e < eb + 32; ++e) {
                int de = sdst_s[e];
                if (de != cur) {
                    atomicMax(&AGG[(size_t)cur * 128 + 64 * ch + c], enc_f32(mx));
                    cur = de;
                    mx = -3.402823466e38f;
                }
                mx = fmaxf(mx, M2[e * 66 + c]);
            }
            atomicMax(&AGG[(size_t)cur * 128 + 64 * ch + c], enc_f32(mx));
        }
        __syncthreads();
    }
}

// ---------------- launch ----------------

extern "C" void kernel_launch(void* const* d_in, const int* in_sizes, int n_in,
                              void* d_out, int out_size, void* d_ws, size_t ws_size,
                              hipStream_t stream) {
    const float* x   = (const float*)d_in[0];
    const int*   ei  = (const int*)d_in[1];
    const float* W1a = (const float*)d_in[2];
    const float* b1a = (const float*)d_in[3];
    const float* W1b = (const float*)d_in[4];
    const float* b1b = (const float*)d_in[5];
    const float* W2a = (const float*)d_in[6];
    const float* b2a = (const float*)d_in[7];
    const float* W2b = (const float*)d_in[8];
    const float* b2b = (const float*)d_in[9];
    const int* src = ei;
    const int* dst = ei + N_EDGES;

    char* ws = (char*)d_ws;
    unsigned short* UV    = (unsigned short*)ws;                 // 25.6 MB (bf16)
    unsigned*       AGG1  = (unsigned*)(ws + 25600000);          // 25.6 MB
    int*            ssrc  = (int*)(ws + 51200000);               // 3.2 MB
    int*            sdst  = (int*)(ws + 54400000);               // 3.2 MB
    unsigned*       count = (unsigned*)(ws + 57600000);          // 200 KB
    unsigned*       cursor= (unsigned*)(ws + 57800000);          // 200 KB
    unsigned short* Wg1   = (unsigned short*)(ws + 58000000);    // 64 KB (Wb1 frags hi|lo)
    unsigned short* Wg2   = (unsigned short*)(ws + 58065536);    // 64 KB
    float*          WC1   = (float*)(ws + 58131072);             // 64 KB
    float*          WC2   = (float*)(ws + 58196608);             // 128 KB
    unsigned short* WCg1  = (unsigned short*)(ws + 58327680);    // 64 KB (frag hi|lo)
    unsigned short* WCg2  = (unsigned short*)(ws + 58393216);    // 128 KB

    const int NH = N_NODES * HID;   // 6.4M

    prep_wcat<<<64, 256, 0, stream>>>(W1a, 64, WC1);
    prep_wcat<<<128, 256, 0, stream>>>(W2a, 128, WC2);
    prep_wfrag<<<64, 256, 0, stream>>>(W1b, Wg1);
    prep_wfrag<<<64, 256, 0, stream>>>(W2b, Wg2);
    prep_wfrag256<<<64, 256, 0, stream>>>(WC1, 64, WCg1);
    prep_wfrag256<<<128, 256, 0, stream>>>(WC2, 128, WCg2);
    fill_u32<<<2048, 256, 0, stream>>>(AGG1, NH, ENC_NEG_INF);
    fill_u32<<<2048, 256, 0, stream>>>((unsigned*)d_out, NH, ENC_NEG_INF);
    fill_u32<<<196, 256, 0, stream>>>(count, N_NODES, 0u);

    // counting sort of edges by dst (max is order-independent -> deterministic)
    hist_dst<<<3125, 256, 0, stream>>>(dst, count);
    scan_offsets<<<1, 1024, 0, stream>>>(count, cursor);
    scatter_edges<<<3125, 256, 0, stream>>>(src, dst, cursor, ssrc, sdst);

    // Layer 1: UV = [x@(W1a_t - W1a_b) + b1a | x@W1a_b]  (bf16, U-bias folded)
    gemm_uv_mfma<0, 2><<<dim3(391, 2), 256, 0, stream>>>(x, WCg1, nullptr, b1a, UV, N_NODES);
    edge_mlp_mfma<<<NWG_E, 256, 0, stream>>>(UV, Wg1, ssrc, sdst, AGG1);

    // Layer 2: H = relu(dec(AGG1) + b1b) fused into A-load
    gemm_uv_mfma<1, 4><<<dim3(391, 2), 256, 0, stream>>>(AGG1, WCg2, b1b, b2a, UV, N_NODES);
    edge_mlp_mfma<<<NWG_E, 256, 0, stream>>>(UV, Wg2, ssrc, sdst, (unsigned*)d_out);
    out_decode<<<2048, 256, 0, stream>>>((unsigned*)d_out, b2b, NH);
}

// Round 7
// 315.521 us; speedup vs baseline: 14.2950x; 1.2631x over previous
//
#include <hip/hip_runtime.h>
#include <stdint.h>

#define N_NODES 50000
#define N_EDGES 800000
#define HID 128
#define NWG_E (N_EDGES / 128)      // 6250 edge blocks
#define XQ (NWG_E / 8)             // 781
#define XR (NWG_E % 8)             // 2
#define SCAN_B 196                 // 196*256 = 50176 >= N_NODES

#define ENC_NEG_INF 0x007FFFFFu   // enc(-inf)

typedef short short8 __attribute__((ext_vector_type(8)));
typedef float f32x4 __attribute__((ext_vector_type(4)));

__device__ __forceinline__ unsigned enc_f32(float f) {
    unsigned u = __float_as_uint(f);
    return (u & 0x80000000u) ? ~u : (u | 0x80000000u);
}
__device__ __forceinline__ float dec_f32(unsigned e) {
    unsigned u = (e & 0x80000000u) ? (e & 0x7FFFFFFFu) : ~e;
    return __uint_as_float(u);
}
__device__ __forceinline__ unsigned short f2bf(float f) {
    unsigned u = __float_as_uint(f);
    unsigned r = (u + 0x7fffu + ((u >> 16) & 1u)) >> 16;
    return (unsigned short)r;
}
__device__ __forceinline__ float bf2f(unsigned short h) {
    return __uint_as_float(((unsigned)h) << 16);
}

// ---------------- utility kernels ----------------

__global__ void fill_u32(unsigned* __restrict__ p, int n, unsigned v) {
    int i = blockIdx.x * blockDim.x + threadIdx.x;
    int stride = gridDim.x * blockDim.x;
    for (; i < n; i += stride) p[i] = v;
}

// Build combined weight WC[K][256]: cols 0..127 = Wtop - Wbot, 128..255 = Wbot
__global__ void prep_wcat(const float* __restrict__ W, int K, float* __restrict__ WC) {
    int idx = blockIdx.x * 256 + threadIdx.x;
    if (idx >= K * 256) return;
    int k = idx >> 8, c = idx & 255;
    float v;
    if (c < 128) v = W[k * 128 + c] - W[(k + K) * 128 + c];
    else         v = W[(k + K) * 128 + (c - 128)];
    WC[idx] = v;
}

// Wb[128][128] -> MFMA B-frag layout (N=128, 8 n-tiles), hi|lo planes of 16384 shorts
__global__ void prep_wfrag(const float* __restrict__ Wb, unsigned short* __restrict__ Wg) {
    int idx = blockIdx.x * 256 + threadIdx.x;   // 0..16383
    int j = idx & 7, lane = (idx >> 3) & 63, nt = (idx >> 9) & 7, kt = idx >> 12;
    int k = 32 * kt + 8 * (lane >> 4) + j;
    int n = 16 * nt + (lane & 15);
    float w = Wb[k * 128 + n];
    unsigned short hi = f2bf(w);
    Wg[idx] = hi;
    Wg[16384 + idx] = f2bf(w - bf2f(hi));
}

// WC[K][256] -> MFMA B-frag layout (N=256, 16 n-tiles), hi plane then lo plane (K*256 each)
__global__ void prep_wfrag256(const float* __restrict__ WC, int K, unsigned short* __restrict__ Wg) {
    int idx = blockIdx.x * 256 + threadIdx.x;
    if (idx >= K * 256) return;
    int j = idx & 7, l = (idx >> 3) & 63, nt = (idx >> 9) & 15, kt = idx >> 13;
    int k = 32 * kt + 8 * (l >> 4) + j;
    int n = 16 * nt + (l & 15);
    float v = WC[k * 256 + n];
    unsigned short hi = f2bf(v);
    Wg[idx] = hi;
    Wg[K * 256 + idx] = f2bf(v - bf2f(hi));
}

// final: encoded u32 -> decoded float + bias; empty segment -> 0
__global__ void out_decode(unsigned* __restrict__ p, const float* __restrict__ bias, int n) {
    int i = blockIdx.x * blockDim.x + threadIdx.x;
    int stride = gridDim.x * blockDim.x;
    for (; i < n; i += stride) {
        unsigned e = p[i];
        float f = (e == ENC_NEG_INF) ? 0.0f : dec_f32(e) + bias[i & 127];
        ((float*)p)[i] = f;
    }
}

// ---------------- sort-by-dst (counting sort, multi-block scan) ----------------

__global__ void hist_dst(const int* __restrict__ dst, unsigned* __restrict__ count) {
    int i = blockIdx.x * blockDim.x + threadIdx.x;
    if (i < N_EDGES) atomicAdd(&count[dst[i]], 1u);
}

// phase 1: per-block sums of count
__global__ __launch_bounds__(256) void scan_p1(const unsigned* __restrict__ count,
                                               unsigned* __restrict__ bsum) {
    __shared__ unsigned s[256];
    int t = threadIdx.x;
    int i = blockIdx.x * 256 + t;
    s[t] = (i < N_NODES) ? count[i] : 0u;
    __syncthreads();
    for (int off = 128; off > 0; off >>= 1) {
        if (t < off) s[t] += s[t + off];
        __syncthreads();
    }
    if (t == 0) bsum[blockIdx.x] = s[0];
}

// phase 2: single block, exclusive scan of the SCAN_B block sums
__global__ __launch_bounds__(256) void scan_p2(unsigned* __restrict__ bsum) {
    __shared__ unsigned s[256];
    int t = threadIdx.x;
    unsigned v = (t < SCAN_B) ? bsum[t] : 0u;
    s[t] = v;
    __syncthreads();
    for (int off = 1; off < 256; off <<= 1) {
        unsigned x = (t >= off) ? s[t - off] : 0u;
        __syncthreads();
        s[t] += x;
        __syncthreads();
    }
    if (t < SCAN_B) bsum[t] = s[t] - v;   // exclusive
}

// phase 3: per-block exclusive scan + block offset -> cursor
__global__ __launch_bounds__(256) void scan_p3(const unsigned* __restrict__ count,
                                               const unsigned* __restrict__ bsum,
                                               unsigned* __restrict__ cursor) {
    __shared__ unsigned s[256];
    int t = threadIdx.x;
    int i = blockIdx.x * 256 + t;
    unsigned v = (i < N_NODES) ? count[i] : 0u;
    s[t] = v;
    __syncthreads();
    for (int off = 1; off < 256; off <<= 1) {
        unsigned x = (t >= off) ? s[t - off] : 0u;
        __syncthreads();
        s[t] += x;
        __syncthreads();
    }
    if (i < N_NODES) cursor[i] = bsum[blockIdx.x] + s[t] - v;
}

__global__ void scatter_edges(const int* __restrict__ src, const int* __restrict__ dst,
                              unsigned* __restrict__ cursor,
                              int* __restrict__ ssrc, int* __restrict__ sdst) {
    int i = blockIdx.x * blockDim.x + threadIdx.x;
    if (i < N_EDGES) {
        int d = dst[i];
        unsigned p = atomicAdd(&cursor[d], 1u);
        ssrc[p] = src[i];
        sdst[p] = d;
    }
}

// ---------------- MFMA node GEMM: C[M][256](bf16) = op(A)[M][K] @ WC[K][256] ----------------
// DEC=0: A f32.  DEC=1: A encoded u32, op = relu(decode + bprev).
template<int DEC, int KT>
__global__ __launch_bounds__(256, 2) void gemm_uv_mfma(
        const void* __restrict__ A_,
        const unsigned short* __restrict__ Wg,   // frag layout, hi|lo planes (K*256 shorts each)
        const float* __restrict__ bprev,         // DEC=1 bias (pre-relu); unused otherwise
        const float* __restrict__ bu,            // U-col bias, applied when by==0
        unsigned short* __restrict__ C,          // [M][256] bf16
        int M) {
    __shared__ char lds[KT * 8192];              // one plane-portion: KT x 8 tiles x 1KB
    const int K = 32 * KT;
    int tid = threadIdx.x;
    int bx = blockIdx.x, by = blockIdx.y;
    int r0 = bx * 128;
    int w = tid >> 6, l = tid & 63;
    int q = l >> 4, m = l & 15;

    // A fragments (bf16 hi)
    short8 ahi[2][KT];
#pragma unroll
    for (int mt = 0; mt < 2; ++mt) {
        int row = r0 + 32 * w + 16 * mt + m;
        bool ok = row < M;
#pragma unroll
        for (int kt = 0; kt < KT; ++kt) {
            float av[8] = {0.f, 0.f, 0.f, 0.f, 0.f, 0.f, 0.f, 0.f};
            if (ok) {
                if (DEC) {
                    const unsigned* Ar = (const unsigned*)A_ + (size_t)row * K + 32 * kt + 8 * q;
                    uint4 x0 = *(const uint4*)Ar;
                    uint4 x1 = *(const uint4*)(Ar + 4);
                    float4 g0 = *(const float4*)&bprev[32 * kt + 8 * q];
                    float4 g1 = *(const float4*)&bprev[32 * kt + 8 * q + 4];
                    av[0] = fmaxf(dec_f32(x0.x) + g0.x, 0.f);
                    av[1] = fmaxf(dec_f32(x0.y) + g0.y, 0.f);
                    av[2] = fmaxf(dec_f32(x0.z) + g0.z, 0.f);
                    av[3] = fmaxf(dec_f32(x0.w) + g0.w, 0.f);
                    av[4] = fmaxf(dec_f32(x1.x) + g1.x, 0.f);
                    av[5] = fmaxf(dec_f32(x1.y) + g1.y, 0.f);
                    av[6] = fmaxf(dec_f32(x1.z) + g1.z, 0.f);
                    av[7] = fmaxf(dec_f32(x1.w) + g1.w, 0.f);
                } else {
                    const float* Ar = (const float*)A_ + (size_t)row * K + 32 * kt + 8 * q;
                    float4 f0 = *(const float4*)Ar;
                    float4 f1 = *(const float4*)(Ar + 4);
                    av[0] = f0.x; av[1] = f0.y; av[2] = f0.z; av[3] = f0.w;
                    av[4] = f1.x; av[5] = f1.y; av[6] = f1.z; av[7] = f1.w;
                }
            }
            short8 hi;
#pragma unroll
            for (int j = 0; j < 8; ++j) hi[j] = (short)f2bf(av[j]);
            ahi[mt][kt] = hi;
        }
    }

    f32x4 acc[2][8];
#pragma unroll
    for (int mt = 0; mt < 2; ++mt)
#pragma unroll
        for (int nt = 0; nt < 8; ++nt)
            acc[mt][nt] = (f32x4){0.f, 0.f, 0.f, 0.f};

    const short8* bfr = (const short8*)lds;

    // two passes: hi plane, then lo plane
#pragma unroll
    for (int pl = 0; pl < 2; ++pl) {
        if (pl) __syncthreads();   // previous readers done
        {
            const float4* s4 = (const float4*)Wg + (size_t)pl * (K * 32);  // plane = K*32 float4
            float4* d4 = (float4*)lds;
#pragma unroll
            for (int it = 0; it < 2 * KT; ++it) {
                int f = 256 * it + tid;
                int tl = f >> 6, fin = f & 63;
                int tg = (tl >> 3) * 16 + 8 * by + (tl & 7);
                d4[f] = s4[tg * 64 + fin];
            }
        }
        __syncthreads();
#pragma unroll
        for (int nt = 0; nt < 8; ++nt)
#pragma unroll
            for (int kt = 0; kt < KT; ++kt) {
                short8 b = bfr[(kt * 8 + nt) * 64 + l];
                acc[0][nt] = __builtin_amdgcn_mfma_f32_16x16x32_bf16(ahi[0][kt], b, acc[0][nt], 0, 0, 0);
                acc[1][nt] = __builtin_amdgcn_mfma_f32_16x16x32_bf16(ahi[1][kt], b, acc[1][nt], 0, 0, 0);
            }
    }

    // epilogue: C[row][128*by + 16nt + m] (D: col=16nt+m, row=4q+r in m-tile)
#pragma unroll
    for (int nt = 0; nt < 8; ++nt) {
        float bias = (by == 0) ? bu[16 * nt + m] : 0.f;
#pragma unroll
        for (int mt = 0; mt < 2; ++mt) {
            int rowb = r0 + 32 * w + 16 * mt + 4 * q;
#pragma unroll
            for (int r = 0; r < 4; ++r) {
                int row = rowb + r;
                if (row < M)
                    C[(size_t)row * 256 + 128 * by + 16 * nt + m] = f2bf(acc[mt][nt][r] + bias);
            }
        }
    }
}

// ---------------- MFMA edge MLP + segmented max-aggregate ----------------
__global__ __launch_bounds__(256, 4) void edge_mlp_mfma(
        const unsigned short* __restrict__ UV, // [N][256] bf16: U 0..127 (incl. ba), V 128..255
        const unsigned short* __restrict__ Wg, // frag layout, hi plane first (16384 shorts)
        const int* __restrict__ ssrc,
        const int* __restrict__ sdst,
        unsigned* __restrict__ AGG) {          // [N][128] encoded (bb added downstream)
    __shared__ char lds[33792];                // union: Whi (32KB) | M2[128][66] f32 chunk
    __shared__ int sdst_s[128];
    int tid = threadIdx.x;
    // bijective XCD-chunked swizzle
    int orig = blockIdx.x;
    int xcd = orig & 7, ii = orig >> 3;
    int wg = (xcd < XR) ? xcd * (XQ + 1) + ii : XR * (XQ + 1) + (xcd - XR) * XQ + ii;
    int e0 = wg * 128;
    int w = tid >> 6, l = tid & 63;
    int q = l >> 4, m = l & 15;

    if (tid < 128) sdst_s[tid] = sdst[e0 + tid];

    // stage W hi plane (32KB)
    {
        const float4* s4 = (const float4*)Wg;
        float4* d4 = (float4*)lds;
#pragma unroll
        for (int i = 0; i < 8; ++i) d4[tid + 256 * i] = s4[tid + 256 * i];
    }

    // build A fragments: t = relu(u + v)
    short8 ahi[2][4];
#pragma unroll
    for (int mt = 0; mt < 2; ++mt) {
        int e = e0 + 32 * w + 16 * mt + m;
        int d = sdst[e], s = ssrc[e];
        const short8* Ud = (const short8*)&UV[(size_t)d * 256];
        const short8* Vs = (const short8*)&UV[(size_t)s * 256 + 128];
#pragma unroll
        for (int kt = 0; kt < 4; ++kt) {
            short8 u8 = Ud[4 * kt + q];
            short8 v8 = Vs[4 * kt + q];
            short8 hi;
#pragma unroll
            for (int j = 0; j < 8; ++j) {
                float t = bf2f((unsigned short)u8[j]) + bf2f((unsigned short)v8[j]);
                hi[j] = (short)f2bf(fmaxf(t, 0.f));
            }
            ahi[mt][kt] = hi;
        }
    }

    f32x4 acc[2][8];
#pragma unroll
    for (int mt = 0; mt < 2; ++mt)
#pragma unroll
        for (int nt = 0; nt < 8; ++nt)
            acc[mt][nt] = (f32x4){0.f, 0.f, 0.f, 0.f};

    const short8* bfr = (const short8*)lds;    // [(kt*8+nt)*64 + lane]

    __syncthreads();   // Whi visible
#pragma unroll
    for (int nt = 0; nt < 8; ++nt)
#pragma unroll
        for (int kt = 0; kt < 4; ++kt) {
            short8 b = bfr[(kt * 8 + nt) * 64 + l];
            acc[0][nt] = __builtin_amdgcn_mfma_f32_16x16x32_bf16(ahi[0][kt], b, acc[0][nt], 0, 0, 0);
            acc[1][nt] = __builtin_amdgcn_mfma_f32_16x16x32_bf16(ahi[1][kt], b, acc[1][nt], 0, 0, 0);
        }
    __syncthreads();   // done reading Whi; LDS free for M2

    // two 64-col chunks: deposit M2[e][c] (stride 66), seg-max reduce
    float* M2 = (float*)lds;
#pragma unroll
    for (int ch = 0; ch < 2; ++ch) {
#pragma unroll
        for (int nt = 0; nt < 4; ++nt) {
            int nn = 4 * ch + nt;
#pragma unroll
            for (int mt = 0; mt < 2; ++mt)
#pragma unroll
                for (int r = 0; r < 4; ++r)
                    M2[(32 * w + 16 * mt + 4 * q + r) * 66 + 16 * nt + m] = acc[mt][nn][r];
        }
        __syncthreads();
        {
            int c = tid & 63, h = tid >> 6;
            int eb = 32 * h;
            int cur = sdst_s[eb];
            float mx = -3.402823466e38f;
            for (int e = eb; e < eb + 32; ++e) {
                int de = sdst_s[e];
                if (de != cur) {
                    atomicMax(&AGG[(size_t)cur * 128 + 64 * ch + c], enc_f32(mx));
                    cur = de;
                    mx = -3.402823466e38f;
                }
                mx = fmaxf(mx, M2[e * 66 + c]);
            }
            atomicMax(&AGG[(size_t)cur * 128 + 64 * ch + c], enc_f32(mx));
        }
        __syncthreads();
    }
}

// ---------------- launch ----------------

extern "C" void kernel_launch(void* const* d_in, const int* in_sizes, int n_in,
                              void* d_out, int out_size, void* d_ws, size_t ws_size,
                              hipStream_t stream) {
    const float* x   = (const float*)d_in[0];
    const int*   ei  = (const int*)d_in[1];
    const float* W1a = (const float*)d_in[2];
    const float* b1a = (const float*)d_in[3];
    const float* W1b = (const float*)d_in[4];
    const float* b1b = (const float*)d_in[5];
    const float* W2a = (const float*)d_in[6];
    const float* b2a = (const float*)d_in[7];
    const float* W2b = (const float*)d_in[8];
    const float* b2b = (const float*)d_in[9];
    const int* src = ei;
    const int* dst = ei + N_EDGES;

    char* ws = (char*)d_ws;
    unsigned short* UV    = (unsigned short*)ws;                 // 25.6 MB (bf16)
    unsigned*       AGG1  = (unsigned*)(ws + 25600000);          // 25.6 MB
    int*            ssrc  = (int*)(ws + 51200000);               // 3.2 MB
    int*            sdst  = (int*)(ws + 54400000);               // 3.2 MB
    unsigned*       count = (unsigned*)(ws + 57600000);          // 200 KB
    unsigned*       cursor= (unsigned*)(ws + 57800000);          // 200 KB
    unsigned short* Wg1   = (unsigned short*)(ws + 58000000);    // 64 KB (Wb1 frags hi|lo)
    unsigned short* Wg2   = (unsigned short*)(ws + 58065536);    // 64 KB
    float*          WC1   = (float*)(ws + 58131072);             // 64 KB
    float*          WC2   = (float*)(ws + 58196608);             // 128 KB
    unsigned short* WCg1  = (unsigned short*)(ws + 58327680);    // 64 KB (frag hi|lo)
    unsigned short* WCg2  = (unsigned short*)(ws + 58393216);    // 128 KB
    unsigned*       bsum  = (unsigned*)(ws + 58655744);          // 1 KB

    const int NH = N_NODES * HID;   // 6.4M

    prep_wcat<<<64, 256, 0, stream>>>(W1a, 64, WC1);
    prep_wcat<<<128, 256, 0, stream>>>(W2a, 128, WC2);
    prep_wfrag<<<64, 256, 0, stream>>>(W1b, Wg1);
    prep_wfrag<<<64, 256, 0, stream>>>(W2b, Wg2);
    prep_wfrag256<<<64, 256, 0, stream>>>(WC1, 64, WCg1);
    prep_wfrag256<<<128, 256, 0, stream>>>(WC2, 128, WCg2);
    fill_u32<<<2048, 256, 0, stream>>>(AGG1, NH, ENC_NEG_INF);
    fill_u32<<<2048, 256, 0, stream>>>((unsigned*)d_out, NH, ENC_NEG_INF);
    fill_u32<<<196, 256, 0, stream>>>(count, N_NODES, 0u);

    // counting sort of edges by dst (max is order-independent -> deterministic)
    hist_dst<<<3125, 256, 0, stream>>>(dst, count);
    scan_p1<<<SCAN_B, 256, 0, stream>>>(count, bsum);
    scan_p2<<<1, 256, 0, stream>>>(bsum);
    scan_p3<<<SCAN_B, 256, 0, stream>>>(count, bsum, cursor);
    scatter_edges<<<3125, 256, 0, stream>>>(src, dst, cursor, ssrc, sdst);

    // Layer 1: UV = [x@(W1a_t - W1a_b) + b1a | x@W1a_b]  (bf16, U-bias folded)
    gemm_uv_mfma<0, 2><<<dim3(391, 2), 256, 0, stream>>>(x, WCg1, nullptr, b1a, UV, N_NODES);
    edge_mlp_mfma<<<NWG_E, 256, 0, stream>>>(UV, Wg1, ssrc, sdst, AGG1);

    // Layer 2: H = relu(dec(AGG1) + b1b) fused into A-load
    gemm_uv_mfma<1, 4><<<dim3(391, 2), 256, 0, stream>>>(AGG1, WCg2, b1b, b2a, UV, N_NODES);
    edge_mlp_mfma<<<NWG_E, 256, 0, stream>>>(UV, Wg2, ssrc, sdst, (unsigned*)d_out);
    out_decode<<<2048, 256, 0, stream>>>((unsigned*)d_out, b2b, NH);
}